// Round 8
// baseline (973.533 us; speedup 1.0000x reference)
//
#include <hip/hip_runtime.h>
#include <hip/hip_bf16.h>
#include <math.h>

#define N_NODES 100000
#define N_EDGES 1600000
#define N_FEAT 64
#define HID 64
#define HL 256
#define N_GRAPHS 512

#define BUCKET_BITS 7
#define BUCKET_SIZE 128
#define NB ((N_NODES + BUCKET_SIZE - 1) / BUCKET_SIZE)   // 782
#define EDGES_PER_BLOCK 4096

// feature-plane layout: 8 planes, plane s = features [8s,8s+8), 16 B per node
#define PSTR ((size_t)N_NODES * 16)   // plane stride in bytes

typedef short vbf8 __attribute__((ext_vector_type(8)));
typedef float vf4 __attribute__((ext_vector_type(4)));

// bf16 helpers (manual RNE; values are finite)
__device__ __forceinline__ unsigned short f2b(float f) {
    unsigned int u = __float_as_uint(f);
    return (unsigned short)((u + 0x7FFFu + ((u >> 16) & 1u)) >> 16);
}
__device__ __forceinline__ float b2f(unsigned short u) {
    return __uint_as_float(((unsigned int)u) << 16);
}

// ---------------- CSR build (bucketed, no per-node global atomics) --------

__global__ __launch_bounds__(256) void k_bhist(const int* __restrict__ dst,
        int* __restrict__ bcnt, int e) {
    __shared__ int lh[NB];
    for (int t = threadIdx.x; t < NB; t += 256) lh[t] = 0;
    __syncthreads();
    int stride = gridDim.x * 256;
    for (int i = blockIdx.x * 256 + threadIdx.x; i < e; i += stride)
        atomicAdd(&lh[dst[i] >> BUCKET_BITS], 1);
    __syncthreads();
    for (int t = threadIdx.x; t < NB; t += 256)
        if (lh[t]) atomicAdd(&bcnt[t], lh[t]);
}

__global__ void k_bscan(const int* __restrict__ bcnt, int* __restrict__ boff,
                        int* __restrict__ bcur, int e) {
    __shared__ int sdata[1024];
    int t = threadIdx.x;
    int v = (t < NB) ? bcnt[t] : 0;
    sdata[t] = v;
    __syncthreads();
    for (int off = 1; off < 1024; off <<= 1) {
        int x = sdata[t];
        int y = (t >= off) ? sdata[t - off] : 0;
        __syncthreads();
        sdata[t] = x + y;
        __syncthreads();
    }
    if (t < NB) {
        int ex = sdata[t] - v;
        boff[t] = ex;
        bcur[t] = ex;
    }
    if (t == 0) boff[NB] = e;
}

__global__ __launch_bounds__(256) void k_bscatter(const int* __restrict__ src,
        const int* __restrict__ dst, int* __restrict__ bcur,
        int2* __restrict__ ebuf, int e) {
    __shared__ int lh[NB];
    __shared__ int lbase[NB];
    for (int t = threadIdx.x; t < NB; t += 256) lh[t] = 0;
    __syncthreads();
    int i0 = blockIdx.x * EDGES_PER_BLOCK;
    int i1 = min(e, i0 + EDGES_PER_BLOCK);
    for (int i = i0 + threadIdx.x; i < i1; i += 256)
        atomicAdd(&lh[dst[i] >> BUCKET_BITS], 1);
    __syncthreads();
    for (int t = threadIdx.x; t < NB; t += 256) {
        int c = lh[t];
        lbase[t] = c ? atomicAdd(&bcur[t], c) : 0;
        lh[t] = 0;  // reuse as local cursor
    }
    __syncthreads();
    for (int i = i0 + threadIdx.x; i < i1; i += 256) {
        int s = src[i], d = dst[i];
        int b = d >> BUCKET_BITS;
        int p = lbase[b] + atomicAdd(&lh[b], 1);
        ebuf[p] = make_int2(s, d);
    }
}

// per-bucket: node hist (LDS) -> block scan -> rowptr write -> scatter soff
// (soff stores plane byte offsets: src*16)
__global__ __launch_bounds__(256) void k_fscatter2(const int2* __restrict__ ebuf,
        const int* __restrict__ boff, int* __restrict__ rowptr,
        unsigned int* __restrict__ soff, int n, int e) {
    __shared__ int lcnt[BUCKET_SIZE];
    __shared__ int sc[BUCKET_SIZE];
    __shared__ int cur[BUCKET_SIZE];
    int b = blockIdx.x;
    int n0 = b * BUCKET_SIZE;
    int t = threadIdx.x;
    if (t < BUCKET_SIZE) lcnt[t] = 0;
    __syncthreads();
    int r0 = boff[b], r1 = boff[b + 1];
    for (int r = r0 + t; r < r1; r += 256) {
        int2 rec = ebuf[r];
        atomicAdd(&lcnt[rec.y - n0], 1);
    }
    __syncthreads();
    int v = 0;
    if (t < BUCKET_SIZE) {
        v = lcnt[t];
        sc[t] = v;
    }
    __syncthreads();
    for (int off = 1; off < BUCKET_SIZE; off <<= 1) {
        int x = 0;
        if (t < BUCKET_SIZE) {
            x = sc[t];
            if (t >= off) x += sc[t - off];
        }
        __syncthreads();
        if (t < BUCKET_SIZE) sc[t] = x;
        __syncthreads();
    }
    if (t < BUCKET_SIZE) {
        int start = r0 + sc[t] - v;   // exclusive
        if (n0 + t < n) rowptr[n0 + t] = start;
        cur[t] = start;
    }
    if (b == 0 && t == 0) rowptr[n] = e;
    __syncthreads();
    for (int r = r0 + t; r < r1; r += 256) {
        int2 rec = ebuf[r];
        int p = atomicAdd(&cur[rec.y - n0], 1);
        soff[p] = (unsigned int)rec.x << 4;
    }
}

// ---------------- fp32 -> bf16 convert into plane layout ----------------

__global__ __launch_bounds__(256) void k_f2b(const float4* __restrict__ x,
        unsigned short* __restrict__ hb, int nq) {   // nq = N*16 float4 quads
    int i = blockIdx.x * 256 + threadIdx.x;
    if (i >= nq) return;
    float4 v = x[i];
    int node = i >> 4, kc = i & 15;     // kc = feature quad (4 features)
    int s = kc >> 1, half = kc & 1;     // plane, half-slice
    uint2 o;
    o.x = (unsigned)f2b(v.x) | ((unsigned)f2b(v.y) << 16);
    o.y = (unsigned)f2b(v.z) | ((unsigned)f2b(v.w) << 16);
    *(uint2*)((char*)hb + (size_t)s * PSTR + (size_t)node * 16 + half * 8) = o;
}

// ---------------- weight prep: Wt[n][k] bf16, k = [wroot 0..63 | wrel 64..127]

__global__ __launch_bounds__(256) void k_wprep(const float* __restrict__ wroot,
        const float* __restrict__ wrel, unsigned short* __restrict__ wt) {
    int i = blockIdx.x * 256 + threadIdx.x;   // 0..8191
    if (i >= 64 * 128) return;
    int nn = i >> 7, k = i & 127;
    float v = (k < 64) ? wroot[k * 64 + nn] : wrel[(k - 64) * 64 + nn];
    wt[i] = f2b(v);
}

// ---------------- aggregation (XCD-sliced planes) ----------------
// block b: slice s = b&7 (maps to one XCD under round-robin dispatch),
// 4 waves = 4 nodes. Lane = q*4+sl: q = edge slot (0..15), sl = dword in the
// 16B slice. One VMEM gather instruction covers 16 edges x 16B. Per-XCD
// gather working set = one 1.6 MB plane -> L2-resident. soff loads and agg
// stores are nontemporal (streaming / consumed by other XCDs).

__global__ __launch_bounds__(256) void k_agg(
    const unsigned short* __restrict__ hb, unsigned short* __restrict__ aggb,
    const int* __restrict__ rowptr, const unsigned int* __restrict__ soff, int n) {
    int lane = threadIdx.x & 63;
    int w = threadIdx.x >> 6;
    int s = blockIdx.x & 7;
    int i = (blockIdx.x >> 3) * 4 + w;
    if (i >= n) return;
    int q = lane >> 2;
    int sl = lane & 3;
    int e0 = rowptr[i], e1 = rowptr[i + 1];
    int iters = (e1 - e0 + 15) >> 4;
    const char* base = (const char*)hb + (size_t)s * PSTR + sl * 4;

    float f0 = 0.f, f1 = 0.f, g0 = 0.f, g1 = 0.f;
    int it = 0;
    for (; it + 2 <= iters; it += 2) {
        int ea = e0 + it * 16 + q;
        int eb = ea + 16;
        unsigned oa = __builtin_nontemporal_load(soff + ea);
        unsigned ob = __builtin_nontemporal_load(soff + eb);
        unsigned da = *(const unsigned*)(base + oa);
        unsigned db = *(const unsigned*)(base + ob);
        if (ea >= e1) da = 0u;
        if (eb >= e1) db = 0u;
        f0 += __uint_as_float(da << 16);
        f1 += __uint_as_float(da & 0xFFFF0000u);
        g0 += __uint_as_float(db << 16);
        g1 += __uint_as_float(db & 0xFFFF0000u);
    }
    if (it < iters) {
        int ea = e0 + it * 16 + q;
        unsigned oa = __builtin_nontemporal_load(soff + ea);
        unsigned da = *(const unsigned*)(base + oa);
        if (ea >= e1) da = 0u;
        f0 += __uint_as_float(da << 16);
        f1 += __uint_as_float(da & 0xFFFF0000u);
    }
    f0 += g0; f1 += g1;
    // fold edge-slot dim (lane bits 2..5)
    f0 += __shfl_xor(f0, 4);  f1 += __shfl_xor(f1, 4);
    f0 += __shfl_xor(f0, 8);  f1 += __shfl_xor(f1, 8);
    f0 += __shfl_xor(f0, 16); f1 += __shfl_xor(f1, 16);
    f0 += __shfl_xor(f0, 32); f1 += __shfl_xor(f1, 32);
    if (q == 0) {
        unsigned o = (unsigned)f2b(f0) | ((unsigned)f2b(f1) << 16);
        __builtin_nontemporal_store(o,
            (unsigned*)((char*)aggb + (size_t)s * PSTR + (size_t)i * 16 + sl * 4));
    }
}

// ---------------- MFMA gemm: hbout = [relu]([hb|aggb] @ Wt^T + brel) -------
// A-fragment k-chunks (8 consecutive features per lane) are exactly one
// plane slice -> direct 16B loads from planes, 256B coalesced per quad.

template <int RELU>
__global__ __launch_bounds__(256) void k_gemm(
    const unsigned short* __restrict__ hb, const unsigned short* __restrict__ aggb,
    const unsigned short* __restrict__ wt, const float* __restrict__ brel,
    unsigned short* __restrict__ hbout, int n) {
    __shared__ float sc[4][16 * 68];

    int tid = threadIdx.x;
    int w = tid >> 6, l = tid & 63;
    int lm = l & 15, q = l >> 4;
    int r0 = blockIdx.x * 64 + w * 16;

    int arow = r0 + lm;
    if (arow >= n) arow = n - 1;
    const char* hp = (const char*)hb + (size_t)arow * 16;
    const char* ap = (const char*)aggb + (size_t)arow * 16;
    vbf8 afr[4];
    afr[0] = *(const vbf8*)(hp + (size_t)q * PSTR);
    afr[1] = *(const vbf8*)(hp + (size_t)(q + 4) * PSTR);
    afr[2] = *(const vbf8*)(ap + (size_t)q * PSTR);
    afr[3] = *(const vbf8*)(ap + (size_t)(q + 4) * PSTR);

    vf4 acc[4];
#pragma unroll
    for (int t = 0; t < 4; t++) acc[t] = (vf4){0.f, 0.f, 0.f, 0.f};

#pragma unroll
    for (int t = 0; t < 4; t++) {
        const unsigned short* wrow = wt + (size_t)(t * 16 + lm) * 128 + q * 8;
#pragma unroll
        for (int s = 0; s < 4; s++) {
            vbf8 bfr = *(const vbf8*)(wrow + s * 32);
            acc[t] = __builtin_amdgcn_mfma_f32_16x16x32_bf16(afr[s], bfr, acc[t], 0, 0, 0);
        }
    }

    float* sw_ = sc[w];
#pragma unroll
    for (int t = 0; t < 4; t++) {
        float b = brel[t * 16 + lm];
#pragma unroll
        for (int i = 0; i < 4; i++) {
            float v = acc[t][i] + b;
            if (RELU) v = fmaxf(v, 0.f);
            sw_[(q * 4 + i) * 68 + t * 16 + lm] = v;
        }
    }
    int rr = l >> 2, cs = l & 3;
    int node = r0 + rr;
    if (node < n) {
        const float* rp = sw_ + rr * 68 + cs * 16;
        float4 v0 = *(const float4*)(rp);
        float4 v1 = *(const float4*)(rp + 4);
        float4 v2 = *(const float4*)(rp + 8);
        float4 v3 = *(const float4*)(rp + 12);
        uint4 o0, o1;
        o0.x = (unsigned)f2b(v0.x) | ((unsigned)f2b(v0.y) << 16);
        o0.y = (unsigned)f2b(v0.z) | ((unsigned)f2b(v0.w) << 16);
        o0.z = (unsigned)f2b(v1.x) | ((unsigned)f2b(v1.y) << 16);
        o0.w = (unsigned)f2b(v1.z) | ((unsigned)f2b(v1.w) << 16);
        o1.x = (unsigned)f2b(v2.x) | ((unsigned)f2b(v2.y) << 16);
        o1.y = (unsigned)f2b(v2.z) | ((unsigned)f2b(v2.w) << 16);
        o1.z = (unsigned)f2b(v3.x) | ((unsigned)f2b(v3.y) << 16);
        o1.w = (unsigned)f2b(v3.z) | ((unsigned)f2b(v3.w) << 16);
        char* outb = (char*)hbout + (size_t)node * 16;
        *(uint4*)(outb + (size_t)(2 * cs) * PSTR) = o0;
        *(uint4*)(outb + (size_t)(2 * cs + 1) * PSTR) = o1;
    }
}

// ---------------- pooling (plane layout reads) ----------------

__global__ void k_bounds(const int* __restrict__ batch, int* __restrict__ gstart,
                         int* __restrict__ gend, int n) {
    int i = blockIdx.x * blockDim.x + threadIdx.x;
    if (i < n) {
        int b = batch[i];
        if (i == 0 || batch[i - 1] != b) gstart[b] = i;
        if (i == n - 1 || batch[i + 1] != b) gend[b] = i + 1;
    }
}

__global__ void k_pool(const unsigned short* __restrict__ hb,
                       const int* __restrict__ gstart,
                       const int* __restrict__ gend, const float* __restrict__ T,
                       float* __restrict__ pool) {
    int g = blockIdx.x;
    int l = threadIdx.x;  // 64 threads; lane l = feature l
    size_t base = (size_t)(l >> 3) * (PSTR / 2) + (l & 7);  // ushort units
    int s0 = gstart[g], s1 = gend[g];
    float s0a = 0.f, s1a = 0.f, s2a = 0.f, s3a = 0.f;
    float m0 = -INFINITY, m1 = -INFINITY, m2 = -INFINITY, m3 = -INFINITY;
    int n = s0;
    for (; n + 4 <= s1; n += 4) {
        float v0 = b2f(hb[base + (size_t)n * 8]);
        float v1 = b2f(hb[base + (size_t)(n + 1) * 8]);
        float v2 = b2f(hb[base + (size_t)(n + 2) * 8]);
        float v3 = b2f(hb[base + (size_t)(n + 3) * 8]);
        s0a += v0; s1a += v1; s2a += v2; s3a += v3;
        m0 = fmaxf(m0, v0); m1 = fmaxf(m1, v1);
        m2 = fmaxf(m2, v2); m3 = fmaxf(m3, v3);
    }
    for (; n < s1; n++) {
        float v = b2f(hb[base + (size_t)n * 8]);
        s0a += v;
        m0 = fmaxf(m0, v);
    }
    float s = (s0a + s1a) + (s2a + s3a);
    float mx = fmaxf(fmaxf(m0, m1), fmaxf(m2, m3));
    int cnt = s1 - s0;
    float mean = s / fmaxf((float)cnt, 1.f);
    if (cnt == 0) mx = 0.f;
    float* row = pool + (size_t)g * 193;
    row[l] = mx;
    row[64 + l] = mean;
    row[128 + l] = s;
    if (l == 0) row[192] = T[g];
}

// ---------------- MLP head ----------------

__global__ __launch_bounds__(256) void k_mlp(
    const float* __restrict__ pool, const float* __restrict__ w1,
    const float* __restrict__ b1, const float* __restrict__ w2,
    const float* __restrict__ b2, const float* __restrict__ w3,
    const float* __restrict__ b3, float* __restrict__ out) {
    __shared__ float sin_[193];
    __shared__ float so1[256];
    __shared__ float red[256];
    int g = blockIdx.x, t = threadIdx.x;
    if (t < 193) sin_[t] = pool[(size_t)g * 193 + t];
    __syncthreads();
    float a = b1[t];
    for (int k = 0; k < 193; k++) a += sin_[k] * w1[k * 256 + t];
    a = fmaxf(a, 0.f);
    so1[t] = a;
    __syncthreads();
    float a2 = b2[t];
    for (int k = 0; k < 256; k++) a2 += so1[k] * w2[k * 256 + t];
    a2 = fmaxf(a2, 0.f);
    red[t] = a2 * w3[t];
    __syncthreads();
    for (int s = 128; s > 0; s >>= 1) {
        if (t < s) red[t] += red[t + s];
        __syncthreads();
    }
    if (t == 0) out[g] = red[0] + b3[0];
}

extern "C" void kernel_launch(void* const* d_in, const int* in_sizes, int n_in,
                              void* d_out, int out_size, void* d_ws, size_t ws_size,
                              hipStream_t stream) {
    const int N = N_NODES, E = N_EDGES, G = N_GRAPHS;

    const float* x = (const float*)d_in[0];
    const int* ei = (const int*)d_in[1];
    const int* batch = (const int*)d_in[2];
    const float* T = (const float*)d_in[3];
    const float* wrel[4] = {(const float*)d_in[4], (const float*)d_in[7],
                            (const float*)d_in[10], (const float*)d_in[13]};
    const float* brel[4] = {(const float*)d_in[5], (const float*)d_in[8],
                            (const float*)d_in[11], (const float*)d_in[14]};
    const float* wroot[4] = {(const float*)d_in[6], (const float*)d_in[9],
                             (const float*)d_in[12], (const float*)d_in[15]};
    const float* w1 = (const float*)d_in[16];
    const float* b1 = (const float*)d_in[17];
    const float* w2 = (const float*)d_in[18];
    const float* b2 = (const float*)d_in[19];
    const float* w3 = (const float*)d_in[20];
    const float* b3 = (const float*)d_in[21];
    float* out = (float*)d_out;

    const int* esrc = ei;
    const int* edst = ei + E;

    // workspace layout
    char* ws = (char*)d_ws;
    size_t off = 0;
    auto alloc = [&](size_t bytes) {
        size_t r = off;
        off = (off + bytes + 255) & ~(size_t)255;
        return r;
    };
    int* rowptr = (int*)(ws + alloc((size_t)(N + 1) * 4));
    int* bcnt = (int*)(ws + alloc((size_t)NB * 4));
    int* boff = (int*)(ws + alloc((size_t)(NB + 1) * 4));
    int* bcur = (int*)(ws + alloc((size_t)NB * 4));
    unsigned int* soff = (unsigned int*)(ws + alloc((size_t)(E + 16) * 4));
    int2* ebuf = (int2*)(ws + alloc((size_t)E * 8));
    unsigned short* hbA = (unsigned short*)(ws + alloc((size_t)N * 64 * 2));
    unsigned short* hbB = (unsigned short*)(ws + alloc((size_t)N * 64 * 2));
    unsigned short* aggb = (unsigned short*)(ws + alloc((size_t)N * 64 * 2));
    unsigned short* wt = (unsigned short*)(ws + alloc((size_t)4 * 64 * 128 * 2));
    int* gstart = (int*)(ws + alloc((size_t)G * 4));
    int* gend = (int*)(ws + alloc((size_t)G * 4));
    float* pool = (float*)(ws + alloc((size_t)G * 193 * 4));

    // 1. CSR build (bucketed)
    hipMemsetAsync(bcnt, 0, (size_t)NB * 4, stream);
    hipMemsetAsync(gstart, 0, (size_t)G * 4, stream);
    hipMemsetAsync(gend, 0, (size_t)G * 4, stream);
    hipMemsetAsync(soff + E, 0, 64, stream);   // pad: tail reads hit plane offset 0
    int hist_blocks = (E + EDGES_PER_BLOCK - 1) / EDGES_PER_BLOCK;  // 391
    k_bhist<<<hist_blocks, 256, 0, stream>>>(edst, bcnt, E);
    k_bscan<<<1, 1024, 0, stream>>>(bcnt, boff, bcur, E);
    k_bscatter<<<hist_blocks, 256, 0, stream>>>(esrc, edst, bcur, ebuf, E);
    k_fscatter2<<<NB, 256, 0, stream>>>(ebuf, boff, rowptr, soff, N, E);

    // 2. convert input + weights to bf16 (plane layout)
    int nq = N * 16;
    k_f2b<<<(nq + 255) / 256, 256, 0, stream>>>((const float4*)x, hbA, nq);
    for (int i = 0; i < 4; i++)
        k_wprep<<<32, 256, 0, stream>>>(wroot[i], wrel[i], wt + i * 64 * 128);

    // 3. four conv layers (bf16 planes ping-pong, MFMA gemm)
    int agg_blocks = ((N + 3) / 4) * 8;      // 4 nodes x 8 slices per block
    int gemm_blocks = (N + 63) / 64;         // 64-node tile per block

    k_agg<<<agg_blocks, 256, 0, stream>>>(hbA, aggb, rowptr, soff, N);
    k_gemm<1><<<gemm_blocks, 256, 0, stream>>>(hbA, aggb, wt + 0 * 8192, brel[0], hbB, N);

    k_agg<<<agg_blocks, 256, 0, stream>>>(hbB, aggb, rowptr, soff, N);
    k_gemm<1><<<gemm_blocks, 256, 0, stream>>>(hbB, aggb, wt + 1 * 8192, brel[1], hbA, N);

    k_agg<<<agg_blocks, 256, 0, stream>>>(hbA, aggb, rowptr, soff, N);
    k_gemm<1><<<gemm_blocks, 256, 0, stream>>>(hbA, aggb, wt + 2 * 8192, brel[2], hbB, N);

    k_agg<<<agg_blocks, 256, 0, stream>>>(hbB, aggb, rowptr, soff, N);
    k_gemm<0><<<gemm_blocks, 256, 0, stream>>>(hbB, aggb, wt + 3 * 8192, brel[3], hbA, N);

    // 4. pooling
    k_bounds<<<(N + 255) / 256, 256, 0, stream>>>(batch, gstart, gend, N);
    k_pool<<<G, 64, 0, stream>>>(hbA, gstart, gend, T, pool);

    // 5. MLP head
    k_mlp<<<G, 256, 0, stream>>>(pool, w1, b1, w2, b2, w3, b3, out);
}

// Round 9
// 608.828 us; speedup vs baseline: 1.5990x; 1.5990x over previous
//
#include <hip/hip_runtime.h>
#include <hip/hip_bf16.h>
#include <math.h>

#define N_NODES 100000
#define N_EDGES 1600000
#define N_FEAT 64
#define HID 64
#define HL 256
#define N_GRAPHS 512

#define BUCKET_BITS 7
#define BUCKET_SIZE 128
#define NB ((N_NODES + BUCKET_SIZE - 1) / BUCKET_SIZE)   // 782
#define EDGES_PER_BLOCK 4096

typedef short vbf8 __attribute__((ext_vector_type(8)));
typedef float vf4 __attribute__((ext_vector_type(4)));

// bf16 helpers (manual RNE; values are finite)
__device__ __forceinline__ unsigned short f2b(float f) {
    unsigned int u = __float_as_uint(f);
    return (unsigned short)((u + 0x7FFFu + ((u >> 16) & 1u)) >> 16);
}
__device__ __forceinline__ float b2f(unsigned short u) {
    return __uint_as_float(((unsigned int)u) << 16);
}

// ---------------- CSR build (bucketed, packed 4B records) ----------------

__global__ __launch_bounds__(256) void k_bhist(const int* __restrict__ dst,
        int* __restrict__ bcnt, int e) {
    __shared__ int lh[NB];
    for (int t = threadIdx.x; t < NB; t += 256) lh[t] = 0;
    __syncthreads();
    int stride = gridDim.x * 256;
    for (int i = blockIdx.x * 256 + threadIdx.x; i < e; i += stride)
        atomicAdd(&lh[dst[i] >> BUCKET_BITS], 1);
    __syncthreads();
    for (int t = threadIdx.x; t < NB; t += 256)
        if (lh[t]) atomicAdd(&bcnt[t], lh[t]);
}

__global__ void k_bscan(const int* __restrict__ bcnt, int* __restrict__ boff,
                        int* __restrict__ bcur, int e) {
    __shared__ int sdata[1024];
    int t = threadIdx.x;
    int v = (t < NB) ? bcnt[t] : 0;
    sdata[t] = v;
    __syncthreads();
    for (int off = 1; off < 1024; off <<= 1) {
        int x = sdata[t];
        int y = (t >= off) ? sdata[t - off] : 0;
        __syncthreads();
        sdata[t] = x + y;
        __syncthreads();
    }
    if (t < NB) {
        int ex = sdata[t] - v;
        boff[t] = ex;
        bcur[t] = ex;
    }
    if (t == 0) boff[NB] = e;
}

// packed record: (src << 7) | (dst & 127)  -- src < 2^17 fits easily
__global__ __launch_bounds__(256) void k_bscatter(const int* __restrict__ src,
        const int* __restrict__ dst, int* __restrict__ bcur,
        unsigned int* __restrict__ ebuf, int e) {
    __shared__ int lh[NB];
    __shared__ int lbase[NB];
    for (int t = threadIdx.x; t < NB; t += 256) lh[t] = 0;
    __syncthreads();
    int i0 = blockIdx.x * EDGES_PER_BLOCK;
    int i1 = min(e, i0 + EDGES_PER_BLOCK);
    for (int i = i0 + threadIdx.x; i < i1; i += 256)
        atomicAdd(&lh[dst[i] >> BUCKET_BITS], 1);
    __syncthreads();
    for (int t = threadIdx.x; t < NB; t += 256) {
        int c = lh[t];
        lbase[t] = c ? atomicAdd(&bcur[t], c) : 0;
        lh[t] = 0;  // reuse as local cursor
    }
    __syncthreads();
    for (int i = i0 + threadIdx.x; i < i1; i += 256) {
        int s = src[i], d = dst[i];
        int b = d >> BUCKET_BITS;
        int p = lbase[b] + atomicAdd(&lh[b], 1);
        ebuf[p] = ((unsigned int)s << 7) | (unsigned int)(d & 127);
    }
}

// per-bucket: node hist (LDS) -> block scan -> rowptr write -> scatter soff
// (soff stores row byte offsets: src*128 == rec & ~127)
__global__ __launch_bounds__(256) void k_fscatter2(const unsigned int* __restrict__ ebuf,
        const int* __restrict__ boff, int* __restrict__ rowptr,
        unsigned int* __restrict__ soff, int n, int e) {
    __shared__ int lcnt[BUCKET_SIZE];
    __shared__ int sc[BUCKET_SIZE];
    __shared__ int cur[BUCKET_SIZE];
    int b = blockIdx.x;
    int n0 = b * BUCKET_SIZE;
    int t = threadIdx.x;
    if (t < BUCKET_SIZE) lcnt[t] = 0;
    __syncthreads();
    int r0 = boff[b], r1 = boff[b + 1];
    for (int r = r0 + t; r < r1; r += 256) {
        unsigned int rec = ebuf[r];
        atomicAdd(&lcnt[rec & 127u], 1);
    }
    __syncthreads();
    int v = 0;
    if (t < BUCKET_SIZE) {
        v = lcnt[t];
        sc[t] = v;
    }
    __syncthreads();
    for (int off = 1; off < BUCKET_SIZE; off <<= 1) {
        int x = 0;
        if (t < BUCKET_SIZE) {
            x = sc[t];
            if (t >= off) x += sc[t - off];
        }
        __syncthreads();
        if (t < BUCKET_SIZE) sc[t] = x;
        __syncthreads();
    }
    if (t < BUCKET_SIZE) {
        int start = r0 + sc[t] - v;   // exclusive
        if (n0 + t < n) rowptr[n0 + t] = start;
        cur[t] = start;
    }
    if (b == 0 && t == 0) rowptr[n] = e;
    __syncthreads();
    for (int r = r0 + t; r < r1; r += 256) {
        unsigned int rec = ebuf[r];
        int p = atomicAdd(&cur[rec & 127u], 1);
        soff[p] = rec & ~127u;   // src * 128 byte offset
    }
}

// ---------------- fp32 -> bf16 convert (layer-0 input, row-major) ---------

__global__ __launch_bounds__(256) void k_f2b(const float4* __restrict__ x,
        ushort4* __restrict__ xb, int nq) {
    int i = blockIdx.x * 256 + threadIdx.x;
    if (i < nq) {
        float4 v = x[i];
        ushort4 o;
        o.x = f2b(v.x); o.y = f2b(v.y); o.z = f2b(v.z); o.w = f2b(v.w);
        xb[i] = o;
    }
}

// ---------------- weight prep: Wt[n][k] bf16, k = [wroot 0..63 | wrel 64..127]

__global__ __launch_bounds__(256) void k_wprep(const float* __restrict__ wroot,
        const float* __restrict__ wrel, unsigned short* __restrict__ wt) {
    int i = blockIdx.x * 256 + threadIdx.x;   // 0..8191
    if (i >= 64 * 128) return;
    int nn = i >> 7, k = i & 127;
    float v = (k < 64) ? wroot[k * 64 + nn] : wrel[(k - 64) * 64 + nn];
    wt[i] = f2b(v);
}

// ---------------- fused conv: agg (to LDS) + MFMA gemm ----------------
// Block = 64 nodes, 4 waves. Wave w aggregates its 16 MFMA rows serially
// (r7 lane layout: q = edge slot 0..3, sl = 8B feature slice 0..15; 4 edges
// per VMEM gather), folds via 2 shfl, writes agg rows to LDS. Barrier, then
// r7 MFMA gemm with agg A-frags read from LDS (saves aggb global roundtrip).

template <int RELU>
__global__ __launch_bounds__(256) void k_conv(
    const unsigned short* __restrict__ hb,
    const unsigned short* __restrict__ wt, const float* __restrict__ brel,
    const int* __restrict__ rowptr, const unsigned int* __restrict__ soff,
    unsigned short* __restrict__ hbout, int n) {
    __shared__ unsigned int sagg[64 * 32];   // 64 nodes x 128 B bf16 agg rows
    __shared__ float sc[4][16 * 68];

    int tid = threadIdx.x;
    int w = tid >> 6, l = tid & 63;
    int r0 = blockIdx.x * 64 + w * 16;

    // ---- agg phase ----
    int q = l >> 4;     // edge slot
    int sl = l & 15;    // 8B feature slice
    const char* gbase = (const char*)hb + sl * 8;

    // prefetch rowptr[r0..r0+16] once per wave
    int rpidx = r0 + (l < 17 ? l : 16);
    if (rpidx > n) rpidx = n;
    int rp = rowptr[rpidx];

    for (int nn = 0; nn < 16; nn++) {
        int i = r0 + nn;
        if (i >= n) break;
        int e0 = __shfl(rp, nn), e1 = __shfl(rp, nn + 1);
        int iters = (e1 - e0 + 3) >> 2;

        float A[4][4];
#pragma unroll
        for (int u = 0; u < 4; u++)
#pragma unroll
            for (int f = 0; f < 4; f++) A[u][f] = 0.f;

        int eq = e0 + q;
        int it = 0;
        for (; it + 4 <= iters; it += 4) {
#pragma unroll
            for (int u = 0; u < 4; u++) {
                int ee = eq + (it + u) * 4;
                unsigned int off = __builtin_nontemporal_load(soff + ee);
                uint2 dv = *(const uint2*)(gbase + off);
                if (ee >= e1) { dv.x = 0u; dv.y = 0u; }
                A[u][0] += __uint_as_float(dv.x << 16);
                A[u][1] += __uint_as_float(dv.x & 0xFFFF0000u);
                A[u][2] += __uint_as_float(dv.y << 16);
                A[u][3] += __uint_as_float(dv.y & 0xFFFF0000u);
            }
        }
        for (; it < iters; it++) {
            int ee = eq + it * 4;
            unsigned int off = __builtin_nontemporal_load(soff + ee);
            uint2 dv = *(const uint2*)(gbase + off);
            if (ee >= e1) { dv.x = 0u; dv.y = 0u; }
            A[0][0] += __uint_as_float(dv.x << 16);
            A[0][1] += __uint_as_float(dv.x & 0xFFFF0000u);
            A[0][2] += __uint_as_float(dv.y << 16);
            A[0][3] += __uint_as_float(dv.y & 0xFFFF0000u);
        }

        float s0 = (A[0][0] + A[1][0]) + (A[2][0] + A[3][0]);
        float s1 = (A[0][1] + A[1][1]) + (A[2][1] + A[3][1]);
        float s2 = (A[0][2] + A[1][2]) + (A[2][2] + A[3][2]);
        float s3 = (A[0][3] + A[1][3]) + (A[2][3] + A[3][3]);
        s0 += __shfl_xor(s0, 16); s0 += __shfl_xor(s0, 32);
        s1 += __shfl_xor(s1, 16); s1 += __shfl_xor(s1, 32);
        s2 += __shfl_xor(s2, 16); s2 += __shfl_xor(s2, 32);
        s3 += __shfl_xor(s3, 16); s3 += __shfl_xor(s3, 32);

        if (q == 0) {
            uint2 o;
            o.x = (unsigned)f2b(s0) | ((unsigned)f2b(s1) << 16);
            o.y = (unsigned)f2b(s2) | ((unsigned)f2b(s3) << 16);
            *(uint2*)((char*)sagg + (size_t)(w * 16 + nn) * 128 + sl * 8) = o;
        }
    }
    __syncthreads();

    // ---- gemm phase (r7 MFMA body; agg A-frags from LDS) ----
    int lm = l & 15;            // == sl
    int arow = r0 + lm;
    if (arow >= n) arow = n - 1;
    const unsigned short* ah = hb + (size_t)arow * 64 + q * 8;
    const unsigned short* sap = (const unsigned short*)sagg +
                                (size_t)(w * 16 + lm) * 64 + q * 8;
    vbf8 afr[4];
    afr[0] = *(const vbf8*)(ah);
    afr[1] = *(const vbf8*)(ah + 32);
    afr[2] = *(const vbf8*)(sap);
    afr[3] = *(const vbf8*)(sap + 32);

    vf4 acc[4];
#pragma unroll
    for (int t = 0; t < 4; t++) acc[t] = (vf4){0.f, 0.f, 0.f, 0.f};

#pragma unroll
    for (int t = 0; t < 4; t++) {
        const unsigned short* wrow = wt + (size_t)(t * 16 + lm) * 128 + q * 8;
#pragma unroll
        for (int s = 0; s < 4; s++) {
            vbf8 bfr = *(const vbf8*)(wrow + s * 32);
            acc[t] = __builtin_amdgcn_mfma_f32_16x16x32_bf16(afr[s], bfr, acc[t], 0, 0, 0);
        }
    }

    float* sw_ = sc[w];
#pragma unroll
    for (int t = 0; t < 4; t++) {
        float b = brel[t * 16 + lm];
#pragma unroll
        for (int i = 0; i < 4; i++) {
            float v = acc[t][i] + b;
            if (RELU) v = fmaxf(v, 0.f);
            sw_[(q * 4 + i) * 68 + t * 16 + lm] = v;
        }
    }
    int rr = l >> 2, cs = l & 3;
    int node = r0 + rr;
    if (node < n) {
        const float* rp2 = sw_ + rr * 68 + cs * 16;
        float4 v0 = *(const float4*)(rp2);
        float4 v1 = *(const float4*)(rp2 + 4);
        float4 v2 = *(const float4*)(rp2 + 8);
        float4 v3 = *(const float4*)(rp2 + 12);
        uint4 o0, o1;
        o0.x = (unsigned)f2b(v0.x) | ((unsigned)f2b(v0.y) << 16);
        o0.y = (unsigned)f2b(v0.z) | ((unsigned)f2b(v0.w) << 16);
        o0.z = (unsigned)f2b(v1.x) | ((unsigned)f2b(v1.y) << 16);
        o0.w = (unsigned)f2b(v1.z) | ((unsigned)f2b(v1.w) << 16);
        o1.x = (unsigned)f2b(v2.x) | ((unsigned)f2b(v2.y) << 16);
        o1.y = (unsigned)f2b(v2.z) | ((unsigned)f2b(v2.w) << 16);
        o1.z = (unsigned)f2b(v3.x) | ((unsigned)f2b(v3.y) << 16);
        o1.w = (unsigned)f2b(v3.z) | ((unsigned)f2b(v3.w) << 16);
        uint4* op = (uint4*)(hbout + (size_t)node * 64 + cs * 16);
        op[0] = o0;
        op[1] = o1;
    }
}

// ---------------- pooling ----------------

__global__ void k_bounds(const int* __restrict__ batch, int* __restrict__ gstart,
                         int* __restrict__ gend, int n) {
    int i = blockIdx.x * blockDim.x + threadIdx.x;
    if (i < n) {
        int b = batch[i];
        if (i == 0 || batch[i - 1] != b) gstart[b] = i;
        if (i == n - 1 || batch[i + 1] != b) gend[b] = i + 1;
    }
}

__global__ void k_pool(const unsigned short* __restrict__ hb,
                       const int* __restrict__ gstart,
                       const int* __restrict__ gend, const float* __restrict__ T,
                       float* __restrict__ pool) {
    int g = blockIdx.x;
    int l = threadIdx.x;  // 64 threads
    int s0 = gstart[g], s1 = gend[g];
    float s0a = 0.f, s1a = 0.f, s2a = 0.f, s3a = 0.f;
    float m0 = -INFINITY, m1 = -INFINITY, m2 = -INFINITY, m3 = -INFINITY;
    int n = s0;
    for (; n + 4 <= s1; n += 4) {
        float v0 = b2f(hb[(size_t)n * 64 + l]);
        float v1 = b2f(hb[(size_t)(n + 1) * 64 + l]);
        float v2 = b2f(hb[(size_t)(n + 2) * 64 + l]);
        float v3 = b2f(hb[(size_t)(n + 3) * 64 + l]);
        s0a += v0; s1a += v1; s2a += v2; s3a += v3;
        m0 = fmaxf(m0, v0); m1 = fmaxf(m1, v1);
        m2 = fmaxf(m2, v2); m3 = fmaxf(m3, v3);
    }
    for (; n < s1; n++) {
        float v = b2f(hb[(size_t)n * 64 + l]);
        s0a += v;
        m0 = fmaxf(m0, v);
    }
    float s = (s0a + s1a) + (s2a + s3a);
    float mx = fmaxf(fmaxf(m0, m1), fmaxf(m2, m3));
    int cnt = s1 - s0;
    float mean = s / fmaxf((float)cnt, 1.f);
    if (cnt == 0) mx = 0.f;
    float* row = pool + (size_t)g * 193;
    row[l] = mx;
    row[64 + l] = mean;
    row[128 + l] = s;
    if (l == 0) row[192] = T[g];
}

// ---------------- MLP head ----------------

__global__ __launch_bounds__(256) void k_mlp(
    const float* __restrict__ pool, const float* __restrict__ w1,
    const float* __restrict__ b1, const float* __restrict__ w2,
    const float* __restrict__ b2, const float* __restrict__ w3,
    const float* __restrict__ b3, float* __restrict__ out) {
    __shared__ float sin_[193];
    __shared__ float so1[256];
    __shared__ float red[256];
    int g = blockIdx.x, t = threadIdx.x;
    if (t < 193) sin_[t] = pool[(size_t)g * 193 + t];
    __syncthreads();
    float a = b1[t];
    for (int k = 0; k < 193; k++) a += sin_[k] * w1[k * 256 + t];
    a = fmaxf(a, 0.f);
    so1[t] = a;
    __syncthreads();
    float a2 = b2[t];
    for (int k = 0; k < 256; k++) a2 += so1[k] * w2[k * 256 + t];
    a2 = fmaxf(a2, 0.f);
    red[t] = a2 * w3[t];
    __syncthreads();
    for (int s = 128; s > 0; s >>= 1) {
        if (t < s) red[t] += red[t + s];
        __syncthreads();
    }
    if (t == 0) out[g] = red[0] + b3[0];
}

extern "C" void kernel_launch(void* const* d_in, const int* in_sizes, int n_in,
                              void* d_out, int out_size, void* d_ws, size_t ws_size,
                              hipStream_t stream) {
    const int N = N_NODES, E = N_EDGES, G = N_GRAPHS;

    const float* x = (const float*)d_in[0];
    const int* ei = (const int*)d_in[1];
    const int* batch = (const int*)d_in[2];
    const float* T = (const float*)d_in[3];
    const float* wrel[4] = {(const float*)d_in[4], (const float*)d_in[7],
                            (const float*)d_in[10], (const float*)d_in[13]};
    const float* brel[4] = {(const float*)d_in[5], (const float*)d_in[8],
                            (const float*)d_in[11], (const float*)d_in[14]};
    const float* wroot[4] = {(const float*)d_in[6], (const float*)d_in[9],
                             (const float*)d_in[12], (const float*)d_in[15]};
    const float* w1 = (const float*)d_in[16];
    const float* b1 = (const float*)d_in[17];
    const float* w2 = (const float*)d_in[18];
    const float* b2 = (const float*)d_in[19];
    const float* w3 = (const float*)d_in[20];
    const float* b3 = (const float*)d_in[21];
    float* out = (float*)d_out;

    const int* esrc = ei;
    const int* edst = ei + E;

    // workspace layout
    char* ws = (char*)d_ws;
    size_t off = 0;
    auto alloc = [&](size_t bytes) {
        size_t r = off;
        off = (off + bytes + 255) & ~(size_t)255;
        return r;
    };
    int* rowptr = (int*)(ws + alloc((size_t)(N + 1) * 4));
    int* bcnt = (int*)(ws + alloc((size_t)NB * 4));
    int* boff = (int*)(ws + alloc((size_t)(NB + 1) * 4));
    int* bcur = (int*)(ws + alloc((size_t)NB * 4));
    unsigned int* soff = (unsigned int*)(ws + alloc((size_t)(E + 16) * 4));
    unsigned int* ebuf = (unsigned int*)(ws + alloc((size_t)E * 4));
    unsigned short* hbA = (unsigned short*)(ws + alloc((size_t)N * 64 * 2));
    unsigned short* hbB = (unsigned short*)(ws + alloc((size_t)N * 64 * 2));
    unsigned short* wt = (unsigned short*)(ws + alloc((size_t)4 * 64 * 128 * 2));
    int* gstart = (int*)(ws + alloc((size_t)G * 4));
    int* gend = (int*)(ws + alloc((size_t)G * 4));
    float* pool = (float*)(ws + alloc((size_t)G * 193 * 4));

    // 1. CSR build (bucketed, packed records)
    hipMemsetAsync(bcnt, 0, (size_t)NB * 4, stream);
    hipMemsetAsync(gstart, 0, (size_t)G * 4, stream);
    hipMemsetAsync(gend, 0, (size_t)G * 4, stream);
    hipMemsetAsync(soff + E, 0, 64, stream);   // pad: tail reads hit row 0
    int hist_blocks = (E + EDGES_PER_BLOCK - 1) / EDGES_PER_BLOCK;  // 391
    k_bhist<<<hist_blocks, 256, 0, stream>>>(edst, bcnt, E);
    k_bscan<<<1, 1024, 0, stream>>>(bcnt, boff, bcur, E);
    k_bscatter<<<hist_blocks, 256, 0, stream>>>(esrc, edst, bcur, ebuf, E);
    k_fscatter2<<<NB, 256, 0, stream>>>(ebuf, boff, rowptr, soff, N, E);

    // 2. convert input + weights to bf16
    int nq = N * 64 / 4;
    k_f2b<<<(nq + 255) / 256, 256, 0, stream>>>((const float4*)x, (ushort4*)hbA, nq);
    for (int i = 0; i < 4; i++)
        k_wprep<<<32, 256, 0, stream>>>(wroot[i], wrel[i], wt + i * 64 * 128);

    // 3. four fused conv layers (bf16 h ping-pong)
    int conv_blocks = (N + 63) / 64;   // 64-node tile per block

    k_conv<1><<<conv_blocks, 256, 0, stream>>>(hbA, wt + 0 * 8192, brel[0], rowptr, soff, hbB, N);
    k_conv<1><<<conv_blocks, 256, 0, stream>>>(hbB, wt + 1 * 8192, brel[1], rowptr, soff, hbA, N);
    k_conv<1><<<conv_blocks, 256, 0, stream>>>(hbA, wt + 2 * 8192, brel[2], rowptr, soff, hbB, N);
    k_conv<0><<<conv_blocks, 256, 0, stream>>>(hbB, wt + 3 * 8192, brel[3], rowptr, soff, hbA, N);

    // 4. pooling
    k_bounds<<<(N + 255) / 256, 256, 0, stream>>>(batch, gstart, gend, N);
    k_pool<<<G, 64, 0, stream>>>(hbA, gstart, gend, T, pool);

    // 5. MLP head
    k_mlp<<<G, 256, 0, stream>>>(pool, w1, b1, w2, b2, w3, b3, out);
}

// Round 10
// 464.852 us; speedup vs baseline: 2.0943x; 1.3097x over previous
//
#include <hip/hip_runtime.h>
#include <hip/hip_bf16.h>
#include <math.h>

#define N_NODES 100000
#define N_EDGES 1600000
#define N_FEAT 64
#define HID 64
#define HL 256
#define N_GRAPHS 512

#define BUCKET_BITS 7
#define BUCKET_SIZE 128
#define NB ((N_NODES + BUCKET_SIZE - 1) / BUCKET_SIZE)   // 782
#define EDGES_PER_BLOCK 4096

typedef short vbf8 __attribute__((ext_vector_type(8)));
typedef float vf4 __attribute__((ext_vector_type(4)));

// bf16 helpers (manual RNE; values are finite)
__device__ __forceinline__ unsigned short f2b(float f) {
    unsigned int u = __float_as_uint(f);
    return (unsigned short)((u + 0x7FFFu + ((u >> 16) & 1u)) >> 16);
}
__device__ __forceinline__ float b2f(unsigned short u) {
    return __uint_as_float(((unsigned int)u) << 16);
}
__device__ __forceinline__ float blo(unsigned int d) {
    return __uint_as_float(d << 16);
}
__device__ __forceinline__ float bhi(unsigned int d) {
    return __uint_as_float(d & 0xFFFF0000u);
}

// ---------------- CSR build (bucketed, packed 4B records) ----------------

__global__ __launch_bounds__(256) void k_bhist(const int* __restrict__ dst,
        int* __restrict__ bcnt, int e) {
    __shared__ int lh[NB];
    for (int t = threadIdx.x; t < NB; t += 256) lh[t] = 0;
    __syncthreads();
    int stride = gridDim.x * 256;
    for (int i = blockIdx.x * 256 + threadIdx.x; i < e; i += stride)
        atomicAdd(&lh[dst[i] >> BUCKET_BITS], 1);
    __syncthreads();
    for (int t = threadIdx.x; t < NB; t += 256)
        if (lh[t]) atomicAdd(&bcnt[t], lh[t]);
}

__global__ void k_bscan(const int* __restrict__ bcnt, int* __restrict__ boff,
                        int* __restrict__ bcur, int e) {
    __shared__ int sdata[1024];
    int t = threadIdx.x;
    int v = (t < NB) ? bcnt[t] : 0;
    sdata[t] = v;
    __syncthreads();
    for (int off = 1; off < 1024; off <<= 1) {
        int x = sdata[t];
        int y = (t >= off) ? sdata[t - off] : 0;
        __syncthreads();
        sdata[t] = x + y;
        __syncthreads();
    }
    if (t < NB) {
        int ex = sdata[t] - v;
        boff[t] = ex;
        bcur[t] = ex;
    }
    if (t == 0) boff[NB] = e;
}

// packed record: (src << 7) | (dst & 127)
__global__ __launch_bounds__(256) void k_bscatter(const int* __restrict__ src,
        const int* __restrict__ dst, int* __restrict__ bcur,
        unsigned int* __restrict__ ebuf, int e) {
    __shared__ int lh[NB];
    __shared__ int lbase[NB];
    for (int t = threadIdx.x; t < NB; t += 256) lh[t] = 0;
    __syncthreads();
    int i0 = blockIdx.x * EDGES_PER_BLOCK;
    int i1 = min(e, i0 + EDGES_PER_BLOCK);
    for (int i = i0 + threadIdx.x; i < i1; i += 256)
        atomicAdd(&lh[dst[i] >> BUCKET_BITS], 1);
    __syncthreads();
    for (int t = threadIdx.x; t < NB; t += 256) {
        int c = lh[t];
        lbase[t] = c ? atomicAdd(&bcur[t], c) : 0;
        lh[t] = 0;  // reuse as local cursor
    }
    __syncthreads();
    for (int i = i0 + threadIdx.x; i < i1; i += 256) {
        int s = src[i], d = dst[i];
        int b = d >> BUCKET_BITS;
        int p = lbase[b] + atomicAdd(&lh[b], 1);
        ebuf[p] = ((unsigned int)s << 7) | (unsigned int)(d & 127);
    }
}

// per-bucket: node hist (LDS) -> block scan -> rowptr write -> scatter soff
// (soff stores row byte offsets: src*128 == rec & ~127). Block 0 also zeroes
// the soff tail pad (replaces a memset dispatch).
__global__ __launch_bounds__(256) void k_fscatter2(const unsigned int* __restrict__ ebuf,
        const int* __restrict__ boff, int* __restrict__ rowptr,
        unsigned int* __restrict__ soff, int n, int e) {
    __shared__ int lcnt[BUCKET_SIZE];
    __shared__ int sc[BUCKET_SIZE];
    __shared__ int cur[BUCKET_SIZE];
    int b = blockIdx.x;
    int n0 = b * BUCKET_SIZE;
    int t = threadIdx.x;
    if (b == 0 && t < 16) soff[e + t] = 0u;   // pad: tail reads hit row 0
    if (t < BUCKET_SIZE) lcnt[t] = 0;
    __syncthreads();
    int r0 = boff[b], r1 = boff[b + 1];
    for (int r = r0 + t; r < r1; r += 256) {
        unsigned int rec = ebuf[r];
        atomicAdd(&lcnt[rec & 127u], 1);
    }
    __syncthreads();
    int v = 0;
    if (t < BUCKET_SIZE) {
        v = lcnt[t];
        sc[t] = v;
    }
    __syncthreads();
    for (int off = 1; off < BUCKET_SIZE; off <<= 1) {
        int x = 0;
        if (t < BUCKET_SIZE) {
            x = sc[t];
            if (t >= off) x += sc[t - off];
        }
        __syncthreads();
        if (t < BUCKET_SIZE) sc[t] = x;
        __syncthreads();
    }
    if (t < BUCKET_SIZE) {
        int start = r0 + sc[t] - v;   // exclusive
        if (n0 + t < n) rowptr[n0 + t] = start;
        cur[t] = start;
    }
    if (b == 0 && t == 0) rowptr[n] = e;
    __syncthreads();
    for (int r = r0 + t; r < r1; r += 256) {
        unsigned int rec = ebuf[r];
        int p = atomicAdd(&cur[rec & 127u], 1);
        soff[p] = rec & ~127u;   // src * 128 byte offset
    }
}

// ---------------- fp32 -> bf16 convert (layer-0 input) ----------------

__global__ __launch_bounds__(256) void k_f2b(const float4* __restrict__ x,
        ushort4* __restrict__ xb, int nq) {
    int i = blockIdx.x * 256 + threadIdx.x;
    if (i < nq) {
        float4 v = x[i];
        ushort4 o;
        o.x = f2b(v.x); o.y = f2b(v.y); o.z = f2b(v.z); o.w = f2b(v.w);
        xb[i] = o;
    }
}

// ---------------- weight prep (all 4 layers in one launch) ----------------
// Wt[layer][n][k] bf16, k = [wroot 0..63 | wrel 64..127]

__global__ __launch_bounds__(256) void k_wprep(
        const float* __restrict__ wroot0, const float* __restrict__ wrel0,
        const float* __restrict__ wroot1, const float* __restrict__ wrel1,
        const float* __restrict__ wroot2, const float* __restrict__ wrel2,
        const float* __restrict__ wroot3, const float* __restrict__ wrel3,
        unsigned short* __restrict__ wt) {
    int gi = blockIdx.x * 256 + threadIdx.x;   // 0..32767
    if (gi >= 4 * 64 * 128) return;
    int layer = gi >> 13;
    int i = gi & 8191;
    int nn = i >> 7, k = i & 127;
    const float* wr = (layer == 0) ? wroot0 : (layer == 1) ? wroot1
                     : (layer == 2) ? wroot2 : wroot3;
    const float* wl = (layer == 0) ? wrel0 : (layer == 1) ? wrel1
                     : (layer == 2) ? wrel2 : wrel3;
    float v = (k < 64) ? wr[k * 64 + nn] : wl[(k - 64) * 64 + nn];
    wt[gi] = f2b(v);
}

// ---------------- aggregation: aggb[i] = sum_{j->i} h[j] (bf16 in/out) -----
// one wave per node; 8 edges per VMEM instruction: lane = q*8+sl,
// q = edge slot (0..7), sl = 16B feature slice (0..7, uint4 load).
// soff holds byte offsets (src*128). Tail edges zeroed (exact +0).

__global__ __launch_bounds__(256) void k_agg(
    const unsigned short* __restrict__ hb, unsigned short* __restrict__ aggb,
    const int* __restrict__ rowptr, const unsigned int* __restrict__ soff, int n) {
    int lane = threadIdx.x & 63;
    int i = (blockIdx.x * 256 + threadIdx.x) >> 6;
    if (i >= n) return;
    int q = lane >> 3;
    int sl = lane & 7;
    int e0 = rowptr[i], e1 = rowptr[i + 1];
    int iters = (e1 - e0 + 7) >> 3;
    const char* base = (const char*)hb + sl * 16;

    float A[8], B[8];
#pragma unroll
    for (int f = 0; f < 8; f++) { A[f] = 0.f; B[f] = 0.f; }

    int eq = e0 + q;
    int it = 0;
    for (; it + 2 <= iters; it += 2) {
        int ea = eq + it * 8, eb = ea + 8;
        unsigned oa = __builtin_nontemporal_load(soff + ea);
        unsigned ob = __builtin_nontemporal_load(soff + eb);
        uint4 da = *(const uint4*)(base + oa);
        uint4 db = *(const uint4*)(base + ob);
        if (ea >= e1) { da.x = 0u; da.y = 0u; da.z = 0u; da.w = 0u; }
        if (eb >= e1) { db.x = 0u; db.y = 0u; db.z = 0u; db.w = 0u; }
        A[0] += blo(da.x); A[1] += bhi(da.x);
        A[2] += blo(da.y); A[3] += bhi(da.y);
        A[4] += blo(da.z); A[5] += bhi(da.z);
        A[6] += blo(da.w); A[7] += bhi(da.w);
        B[0] += blo(db.x); B[1] += bhi(db.x);
        B[2] += blo(db.y); B[3] += bhi(db.y);
        B[4] += blo(db.z); B[5] += bhi(db.z);
        B[6] += blo(db.w); B[7] += bhi(db.w);
    }
    if (it < iters) {
        int ea = eq + it * 8;
        unsigned oa = __builtin_nontemporal_load(soff + ea);
        uint4 da = *(const uint4*)(base + oa);
        if (ea >= e1) { da.x = 0u; da.y = 0u; da.z = 0u; da.w = 0u; }
        A[0] += blo(da.x); A[1] += bhi(da.x);
        A[2] += blo(da.y); A[3] += bhi(da.y);
        A[4] += blo(da.z); A[5] += bhi(da.z);
        A[6] += blo(da.w); A[7] += bhi(da.w);
    }

    float f[8];
#pragma unroll
    for (int k = 0; k < 8; k++) {
        float s = A[k] + B[k];
        s += __shfl_xor(s, 8);
        s += __shfl_xor(s, 16);
        s += __shfl_xor(s, 32);
        f[k] = s;
    }
    if (q == 0) {
        uint4 o;
        o.x = (unsigned)f2b(f[0]) | ((unsigned)f2b(f[1]) << 16);
        o.y = (unsigned)f2b(f[2]) | ((unsigned)f2b(f[3]) << 16);
        o.z = (unsigned)f2b(f[4]) | ((unsigned)f2b(f[5]) << 16);
        o.w = (unsigned)f2b(f[6]) | ((unsigned)f2b(f[7]) << 16);
        *(uint4*)((char*)aggb + (size_t)i * 128 + sl * 16) = o;
    }
}

// ---------------- MFMA gemm: hbout = [relu]([hb|aggb] @ Wt^T + brel) -------

template <int RELU>
__global__ __launch_bounds__(256) void k_gemm(
    const unsigned short* __restrict__ hb, const unsigned short* __restrict__ aggb,
    const unsigned short* __restrict__ wt, const float* __restrict__ brel,
    unsigned short* __restrict__ hbout, int n) {
    __shared__ float sc[4][16 * 68];

    int tid = threadIdx.x;
    int w = tid >> 6, l = tid & 63;
    int lm = l & 15, q = l >> 4;
    int r0 = blockIdx.x * 64 + w * 16;

    int arow = r0 + lm;
    if (arow >= n) arow = n - 1;
    const unsigned short* ah = hb + (size_t)arow * 64 + q * 8;
    const unsigned short* aa = aggb + (size_t)arow * 64 + q * 8;
    vbf8 afr[4];
    afr[0] = *(const vbf8*)(ah);
    afr[1] = *(const vbf8*)(ah + 32);
    afr[2] = *(const vbf8*)(aa);
    afr[3] = *(const vbf8*)(aa + 32);

    vf4 acc[4];
#pragma unroll
    for (int t = 0; t < 4; t++) acc[t] = (vf4){0.f, 0.f, 0.f, 0.f};

#pragma unroll
    for (int t = 0; t < 4; t++) {
        const unsigned short* wrow = wt + (size_t)(t * 16 + lm) * 128 + q * 8;
#pragma unroll
        for (int s = 0; s < 4; s++) {
            vbf8 bfr = *(const vbf8*)(wrow + s * 32);
            acc[t] = __builtin_amdgcn_mfma_f32_16x16x32_bf16(afr[s], bfr, acc[t], 0, 0, 0);
        }
    }

    float* sw_ = sc[w];
#pragma unroll
    for (int t = 0; t < 4; t++) {
        float b = brel[t * 16 + lm];
#pragma unroll
        for (int i = 0; i < 4; i++) {
            float v = acc[t][i] + b;
            if (RELU) v = fmaxf(v, 0.f);
            sw_[(q * 4 + i) * 68 + t * 16 + lm] = v;
        }
    }
    int rr = l >> 2, cs = l & 3;
    int node = r0 + rr;
    if (node < n) {
        const float* rp = sw_ + rr * 68 + cs * 16;
        float4 v0 = *(const float4*)(rp);
        float4 v1 = *(const float4*)(rp + 4);
        float4 v2 = *(const float4*)(rp + 8);
        float4 v3 = *(const float4*)(rp + 12);
        uint4 o0, o1;
        o0.x = (unsigned)f2b(v0.x) | ((unsigned)f2b(v0.y) << 16);
        o0.y = (unsigned)f2b(v0.z) | ((unsigned)f2b(v0.w) << 16);
        o0.z = (unsigned)f2b(v1.x) | ((unsigned)f2b(v1.y) << 16);
        o0.w = (unsigned)f2b(v1.z) | ((unsigned)f2b(v1.w) << 16);
        o1.x = (unsigned)f2b(v2.x) | ((unsigned)f2b(v2.y) << 16);
        o1.y = (unsigned)f2b(v2.z) | ((unsigned)f2b(v2.w) << 16);
        o1.z = (unsigned)f2b(v3.x) | ((unsigned)f2b(v3.y) << 16);
        o1.w = (unsigned)f2b(v3.z) | ((unsigned)f2b(v3.w) << 16);
        uint4* op = (uint4*)(hbout + (size_t)node * 64 + cs * 16);
        op[0] = o0;
        op[1] = o1;
    }
}

// ---------------- pooling (binary search on sorted batch) ----------------

__global__ void k_pool(const unsigned short* __restrict__ hb,
                       const int* __restrict__ batch, const float* __restrict__ T,
                       float* __restrict__ pool, int n) {
    int g = blockIdx.x;
    int l = threadIdx.x;  // 64 threads
    // lower_bound(batch, g) and lower_bound(batch, g+1); batch sorted.
    int lo = 0, hi = n;
    while (lo < hi) { int m = (lo + hi) >> 1; if (batch[m] < g) lo = m + 1; else hi = m; }
    int s0 = lo;
    int lo2 = s0, hi2 = n;
    while (lo2 < hi2) { int m = (lo2 + hi2) >> 1; if (batch[m] < g + 1) lo2 = m + 1; else hi2 = m; }
    int s1 = lo2;

    float s0a = 0.f, s1a = 0.f, s2a = 0.f, s3a = 0.f;
    float m0 = -INFINITY, m1 = -INFINITY, m2 = -INFINITY, m3 = -INFINITY;
    int nn = s0;
    for (; nn + 4 <= s1; nn += 4) {
        float v0 = b2f(hb[(size_t)nn * 64 + l]);
        float v1 = b2f(hb[(size_t)(nn + 1) * 64 + l]);
        float v2 = b2f(hb[(size_t)(nn + 2) * 64 + l]);
        float v3 = b2f(hb[(size_t)(nn + 3) * 64 + l]);
        s0a += v0; s1a += v1; s2a += v2; s3a += v3;
        m0 = fmaxf(m0, v0); m1 = fmaxf(m1, v1);
        m2 = fmaxf(m2, v2); m3 = fmaxf(m3, v3);
    }
    for (; nn < s1; nn++) {
        float v = b2f(hb[(size_t)nn * 64 + l]);
        s0a += v;
        m0 = fmaxf(m0, v);
    }
    float s = (s0a + s1a) + (s2a + s3a);
    float mx = fmaxf(fmaxf(m0, m1), fmaxf(m2, m3));
    int cnt = s1 - s0;
    float mean = s / fmaxf((float)cnt, 1.f);
    if (cnt == 0) mx = 0.f;
    float* row = pool + (size_t)g * 193;
    row[l] = mx;
    row[64 + l] = mean;
    row[128 + l] = s;
    if (l == 0) row[192] = T[g];
}

// ---------------- MLP head ----------------

__global__ __launch_bounds__(256) void k_mlp(
    const float* __restrict__ pool, const float* __restrict__ w1,
    const float* __restrict__ b1, const float* __restrict__ w2,
    const float* __restrict__ b2, const float* __restrict__ w3,
    const float* __restrict__ b3, float* __restrict__ out) {
    __shared__ float sin_[193];
    __shared__ float so1[256];
    __shared__ float red[256];
    int g = blockIdx.x, t = threadIdx.x;
    if (t < 193) sin_[t] = pool[(size_t)g * 193 + t];
    __syncthreads();
    float a = b1[t];
    for (int k = 0; k < 193; k++) a += sin_[k] * w1[k * 256 + t];
    a = fmaxf(a, 0.f);
    so1[t] = a;
    __syncthreads();
    float a2 = b2[t];
    for (int k = 0; k < 256; k++) a2 += so1[k] * w2[k * 256 + t];
    a2 = fmaxf(a2, 0.f);
    red[t] = a2 * w3[t];
    __syncthreads();
    for (int s = 128; s > 0; s >>= 1) {
        if (t < s) red[t] += red[t + s];
        __syncthreads();
    }
    if (t == 0) out[g] = red[0] + b3[0];
}

extern "C" void kernel_launch(void* const* d_in, const int* in_sizes, int n_in,
                              void* d_out, int out_size, void* d_ws, size_t ws_size,
                              hipStream_t stream) {
    const int N = N_NODES, E = N_EDGES, G = N_GRAPHS;

    const float* x = (const float*)d_in[0];
    const int* ei = (const int*)d_in[1];
    const int* batch = (const int*)d_in[2];
    const float* T = (const float*)d_in[3];
    const float* wrel[4] = {(const float*)d_in[4], (const float*)d_in[7],
                            (const float*)d_in[10], (const float*)d_in[13]};
    const float* brel[4] = {(const float*)d_in[5], (const float*)d_in[8],
                            (const float*)d_in[11], (const float*)d_in[14]};
    const float* wroot[4] = {(const float*)d_in[6], (const float*)d_in[9],
                             (const float*)d_in[12], (const float*)d_in[15]};
    const float* w1 = (const float*)d_in[16];
    const float* b1 = (const float*)d_in[17];
    const float* w2 = (const float*)d_in[18];
    const float* b2 = (const float*)d_in[19];
    const float* w3 = (const float*)d_in[20];
    const float* b3 = (const float*)d_in[21];
    float* out = (float*)d_out;

    const int* esrc = ei;
    const int* edst = ei + E;

    // workspace layout
    char* ws = (char*)d_ws;
    size_t off = 0;
    auto alloc = [&](size_t bytes) {
        size_t r = off;
        off = (off + bytes + 255) & ~(size_t)255;
        return r;
    };
    int* rowptr = (int*)(ws + alloc((size_t)(N + 1) * 4));
    int* bcnt = (int*)(ws + alloc((size_t)NB * 4));
    int* boff = (int*)(ws + alloc((size_t)(NB + 1) * 4));
    int* bcur = (int*)(ws + alloc((size_t)NB * 4));
    unsigned int* soff = (unsigned int*)(ws + alloc((size_t)(E + 16) * 4));
    unsigned int* ebuf = (unsigned int*)(ws + alloc((size_t)E * 4));
    unsigned short* hbA = (unsigned short*)(ws + alloc((size_t)N * 64 * 2));
    unsigned short* hbB = (unsigned short*)(ws + alloc((size_t)N * 64 * 2));
    unsigned short* aggb = (unsigned short*)(ws + alloc((size_t)N * 64 * 2));
    unsigned short* wt = (unsigned short*)(ws + alloc((size_t)4 * 64 * 128 * 2));
    float* pool = (float*)(ws + alloc((size_t)G * 193 * 4));

    // 1. CSR build (bucketed, packed records)
    hipMemsetAsync(bcnt, 0, (size_t)NB * 4, stream);
    int hist_blocks = (E + EDGES_PER_BLOCK - 1) / EDGES_PER_BLOCK;  // 391
    k_bhist<<<hist_blocks, 256, 0, stream>>>(edst, bcnt, E);
    k_bscan<<<1, 1024, 0, stream>>>(bcnt, boff, bcur, E);
    k_bscatter<<<hist_blocks, 256, 0, stream>>>(esrc, edst, bcur, ebuf, E);
    k_fscatter2<<<NB, 256, 0, stream>>>(ebuf, boff, rowptr, soff, N, E);

    // 2. convert input + weights to bf16
    int nq = N * 64 / 4;
    k_f2b<<<(nq + 255) / 256, 256, 0, stream>>>((const float4*)x, (ushort4*)hbA, nq);
    k_wprep<<<128, 256, 0, stream>>>(wroot[0], wrel[0], wroot[1], wrel[1],
                                     wroot[2], wrel[2], wroot[3], wrel[3], wt);

    // 3. four conv layers (bf16 h ping-pong, MFMA gemm)
    int agg_blocks = (N * 64 + 255) / 256;   // one wave per node
    int gemm_blocks = (N + 63) / 64;         // 64-node tile per block

    k_agg<<<agg_blocks, 256, 0, stream>>>(hbA, aggb, rowptr, soff, N);
    k_gemm<1><<<gemm_blocks, 256, 0, stream>>>(hbA, aggb, wt + 0 * 8192, brel[0], hbB, N);

    k_agg<<<agg_blocks, 256, 0, stream>>>(hbB, aggb, rowptr, soff, N);
    k_gemm<1><<<gemm_blocks, 256, 0, stream>>>(hbB, aggb, wt + 1 * 8192, brel[1], hbA, N);

    k_agg<<<agg_blocks, 256, 0, stream>>>(hbA, aggb, rowptr, soff, N);
    k_gemm<1><<<gemm_blocks, 256, 0, stream>>>(hbA, aggb, wt + 2 * 8192, brel[2], hbB, N);

    k_agg<<<agg_blocks, 256, 0, stream>>>(hbB, aggb, rowptr, soff, N);
    k_gemm<0><<<gemm_blocks, 256, 0, stream>>>(hbB, aggb, wt + 3 * 8192, brel[3], hbA, N);

    // 4. pooling (binary-search bounds; no k_bounds / memsets)
    k_pool<<<G, 64, 0, stream>>>(hbA, batch, T, pool, N);

    // 5. MLP head
    k_mlp<<<G, 256, 0, stream>>>(pool, w1, b1, w2, b2, w3, b3, out);
}

// Round 11
// 429.882 us; speedup vs baseline: 2.2647x; 1.0813x over previous
//
#include <hip/hip_runtime.h>
#include <hip/hip_bf16.h>
#include <math.h>

#define N_NODES 100000
#define N_EDGES 1600000
#define N_FEAT 64
#define HID 64
#define HL 256
#define N_GRAPHS 512

#define BUCKET_BITS 7
#define BUCKET_SIZE 128
#define NB ((N_NODES + BUCKET_SIZE - 1) / BUCKET_SIZE)   // 782
#define CAP 2560                   // per-bucket record capacity (mean 2046 + 11 sigma)
#define EDGES_PER_BLOCK 4096
#define SCAT_BLOCKS ((N_EDGES + EDGES_PER_BLOCK - 1) / EDGES_PER_BLOCK)  // 391
#define F2B_BLOCKS (N_NODES * 16 / 256)                                  // 6250
#define WPREP_BLOCKS 128

typedef short vbf8 __attribute__((ext_vector_type(8)));
typedef float vf4 __attribute__((ext_vector_type(4)));
typedef float vf2 __attribute__((ext_vector_type(2)));

// bf16 helpers (manual RNE; values are finite)
__device__ __forceinline__ unsigned short f2b(float f) {
    unsigned int u = __float_as_uint(f);
    return (unsigned short)((u + 0x7FFFu + ((u >> 16) & 1u)) >> 16);
}
__device__ __forceinline__ float b2f(unsigned short u) {
    return __uint_as_float(((unsigned int)u) << 16);
}
// bf16 pair -> float2 {lo, hi} (shift + and; pairs with v_pk_add_f32)
__device__ __forceinline__ vf2 bpair(unsigned int d) {
    vf2 r;
    r.x = __uint_as_float(d << 16);
    r.y = __uint_as_float(d & 0xFFFF0000u);
    return r;
}

// ---------------- mega prep: bucket-scatter + f2b + wprep in one launch ----

__global__ __launch_bounds__(256) void k_mega(
        const int* __restrict__ src, const int* __restrict__ dst,
        int* __restrict__ bcnt, unsigned int* __restrict__ ebuf,
        const float4* __restrict__ x, ushort4* __restrict__ xb,
        const float* __restrict__ wroot0, const float* __restrict__ wrel0,
        const float* __restrict__ wroot1, const float* __restrict__ wrel1,
        const float* __restrict__ wroot2, const float* __restrict__ wrel2,
        const float* __restrict__ wroot3, const float* __restrict__ wrel3,
        unsigned short* __restrict__ wt) {
    __shared__ int lh[NB];
    __shared__ int lbase[NB];
    int bid = blockIdx.x;
    int t = threadIdx.x;

    if (bid < SCAT_BLOCKS) {
        // ---- bucket scatter: packed record (src<<7)|(dst&127), fixed CAP ----
        for (int i = t; i < NB; i += 256) lh[i] = 0;
        __syncthreads();
        int i0 = bid * EDGES_PER_BLOCK;
        int i1 = min(N_EDGES, i0 + EDGES_PER_BLOCK);
        for (int i = i0 + t; i < i1; i += 256)
            atomicAdd(&lh[dst[i] >> BUCKET_BITS], 1);
        __syncthreads();
        for (int i = t; i < NB; i += 256) {
            int c = lh[i];
            lbase[i] = c ? atomicAdd(&bcnt[i], c) : 0;
            lh[i] = 0;  // reuse as local cursor
        }
        __syncthreads();
        for (int i = i0 + t; i < i1; i += 256) {
            int s = src[i], d = dst[i];
            int b = d >> BUCKET_BITS;
            int p = b * CAP + lbase[b] + atomicAdd(&lh[b], 1);
            ebuf[p] = ((unsigned int)s << 7) | (unsigned int)(d & 127);
        }
    } else if (bid < SCAT_BLOCKS + F2B_BLOCKS) {
        // ---- fp32 -> bf16 convert ----
        int i = (bid - SCAT_BLOCKS) * 256 + t;
        if (i < N_NODES * 16) {
            float4 v = x[i];
            ushort4 o;
            o.x = f2b(v.x); o.y = f2b(v.y); o.z = f2b(v.z); o.w = f2b(v.w);
            xb[i] = o;
        }
    } else {
        // ---- weight prep: Wt[layer][n][k], k = [wroot|wrel] ----
        int gi = (bid - SCAT_BLOCKS - F2B_BLOCKS) * 256 + t;
        if (gi < 4 * 64 * 128) {
            int layer = gi >> 13;
            int i = gi & 8191;
            int nn = i >> 7, k = i & 127;
            const float* wr = (layer == 0) ? wroot0 : (layer == 1) ? wroot1
                             : (layer == 2) ? wroot2 : wroot3;
            const float* wl = (layer == 0) ? wrel0 : (layer == 1) ? wrel1
                             : (layer == 2) ? wrel2 : wrel3;
            float v = (k < 64) ? wr[k * 64 + nn] : wl[(k - 64) * 64 + nn];
            wt[gi] = f2b(v);
        }
    }
}

// ---------------- per-bucket: node hist -> scan -> re{start,end} -> soff ---
// soff stays bucket-padded: node i's edges at [re[i].x, re[i].y) within the
// bucket's CAP region. 8-entry zero tail per bucket keeps agg over-reads safe.

__global__ __launch_bounds__(256) void k_fscatter2(const unsigned int* __restrict__ ebuf,
        const int* __restrict__ bcnt, int2* __restrict__ re,
        unsigned int* __restrict__ soff, int n) {
    __shared__ int lcnt[BUCKET_SIZE];
    __shared__ int sc[BUCKET_SIZE];
    __shared__ int cur[BUCKET_SIZE];
    int b = blockIdx.x;
    int rbase = b * CAP;
    int n0 = b * BUCKET_SIZE;
    int t = threadIdx.x;
    int cb = bcnt[b];
    if (t < BUCKET_SIZE) lcnt[t] = 0;
    __syncthreads();
    for (int r = t; r < cb; r += 256) {
        unsigned int rec = ebuf[rbase + r];
        atomicAdd(&lcnt[rec & 127u], 1);
    }
    __syncthreads();
    int v = 0;
    if (t < BUCKET_SIZE) {
        v = lcnt[t];
        sc[t] = v;
    }
    __syncthreads();
    for (int off = 1; off < BUCKET_SIZE; off <<= 1) {
        int x = 0;
        if (t < BUCKET_SIZE) {
            x = sc[t];
            if (t >= off) x += sc[t - off];
        }
        __syncthreads();
        if (t < BUCKET_SIZE) sc[t] = x;
        __syncthreads();
    }
    if (t < BUCKET_SIZE) {
        int start = rbase + sc[t] - v;   // exclusive scan
        if (n0 + t < n) re[n0 + t] = make_int2(start, start + v);
        cur[t] = start;
    }
    __syncthreads();
    for (int r = t; r < cb; r += 256) {
        unsigned int rec = ebuf[rbase + r];
        int p = atomicAdd(&cur[rec & 127u], 1);
        soff[p] = rec & ~127u;   // src * 128 byte offset
    }
    if (t < 8) soff[rbase + cb + t] = 0u;   // zero tail pad for agg over-reads
}

// ---------------- aggregation: aggb[i] = sum_{j->i} h[j] (bf16 in/out) -----
// one wave per node; 8 edges per VMEM instruction: lane = q*8+sl,
// q = edge slot (0..7), sl = 16B feature slice (0..7, uint4 load).
// float2 accumulators -> v_pk_add_f32 (12 VALU per uint4 vs 16 scalar).

__global__ __launch_bounds__(256) void k_agg(
    const unsigned short* __restrict__ hb, unsigned short* __restrict__ aggb,
    const int2* __restrict__ re, const unsigned int* __restrict__ soff, int n) {
    int lane = threadIdx.x & 63;
    int i = (blockIdx.x * 256 + threadIdx.x) >> 6;
    if (i >= n) return;
    int q = lane >> 3;
    int sl = lane & 7;
    int2 bounds = re[i];
    int e0 = bounds.x, e1 = bounds.y;
    int iters = (e1 - e0 + 7) >> 3;
    const char* base = (const char*)hb + sl * 16;

    vf2 A[4], B[4];
#pragma unroll
    for (int f = 0; f < 4; f++) { A[f] = (vf2){0.f, 0.f}; B[f] = (vf2){0.f, 0.f}; }

    int eq = e0 + q;
    int it = 0;
    for (; it + 2 <= iters; it += 2) {
        int ea = eq + it * 8, eb = ea + 8;
        unsigned oa = __builtin_nontemporal_load(soff + ea);
        unsigned ob = __builtin_nontemporal_load(soff + eb);
        uint4 da = *(const uint4*)(base + oa);
        uint4 db = *(const uint4*)(base + ob);
        if (ea >= e1) { da.x = 0u; da.y = 0u; da.z = 0u; da.w = 0u; }
        if (eb >= e1) { db.x = 0u; db.y = 0u; db.z = 0u; db.w = 0u; }
        A[0] += bpair(da.x); A[1] += bpair(da.y);
        A[2] += bpair(da.z); A[3] += bpair(da.w);
        B[0] += bpair(db.x); B[1] += bpair(db.y);
        B[2] += bpair(db.z); B[3] += bpair(db.w);
    }
    if (it < iters) {
        int ea = eq + it * 8;
        unsigned oa = __builtin_nontemporal_load(soff + ea);
        uint4 da = *(const uint4*)(base + oa);
        if (ea >= e1) { da.x = 0u; da.y = 0u; da.z = 0u; da.w = 0u; }
        A[0] += bpair(da.x); A[1] += bpair(da.y);
        A[2] += bpair(da.z); A[3] += bpair(da.w);
    }

    float f[8];
#pragma unroll
    for (int k = 0; k < 4; k++) {
        vf2 s2 = A[k] + B[k];
        float slo = s2.x, shi = s2.y;
        slo += __shfl_xor(slo, 8);
        slo += __shfl_xor(slo, 16);
        slo += __shfl_xor(slo, 32);
        shi += __shfl_xor(shi, 8);
        shi += __shfl_xor(shi, 16);
        shi += __shfl_xor(shi, 32);
        f[2 * k] = slo;
        f[2 * k + 1] = shi;
    }
    if (q == 0) {
        uint4 o;
        o.x = (unsigned)f2b(f[0]) | ((unsigned)f2b(f[1]) << 16);
        o.y = (unsigned)f2b(f[2]) | ((unsigned)f2b(f[3]) << 16);
        o.z = (unsigned)f2b(f[4]) | ((unsigned)f2b(f[5]) << 16);
        o.w = (unsigned)f2b(f[6]) | ((unsigned)f2b(f[7]) << 16);
        *(uint4*)((char*)aggb + (size_t)i * 128 + sl * 16) = o;
    }
}

// ---------------- MFMA gemm: hbout = [relu]([hb|aggb] @ Wt^T + brel) -------

template <int RELU>
__global__ __launch_bounds__(256) void k_gemm(
    const unsigned short* __restrict__ hb, const unsigned short* __restrict__ aggb,
    const unsigned short* __restrict__ wt, const float* __restrict__ brel,
    unsigned short* __restrict__ hbout, int n) {
    __shared__ float sc[4][16 * 68];

    int tid = threadIdx.x;
    int w = tid >> 6, l = tid & 63;
    int lm = l & 15, q = l >> 4;
    int r0 = blockIdx.x * 64 + w * 16;

    int arow = r0 + lm;
    if (arow >= n) arow = n - 1;
    const unsigned short* ah = hb + (size_t)arow * 64 + q * 8;
    const unsigned short* aa = aggb + (size_t)arow * 64 + q * 8;
    vbf8 afr[4];
    afr[0] = *(const vbf8*)(ah);
    afr[1] = *(const vbf8*)(ah + 32);
    afr[2] = *(const vbf8*)(aa);
    afr[3] = *(const vbf8*)(aa + 32);

    vf4 acc[4];
#pragma unroll
    for (int t = 0; t < 4; t++) acc[t] = (vf4){0.f, 0.f, 0.f, 0.f};

#pragma unroll
    for (int t = 0; t < 4; t++) {
        const unsigned short* wrow = wt + (size_t)(t * 16 + lm) * 128 + q * 8;
#pragma unroll
        for (int s = 0; s < 4; s++) {
            vbf8 bfr = *(const vbf8*)(wrow + s * 32);
            acc[t] = __builtin_amdgcn_mfma_f32_16x16x32_bf16(afr[s], bfr, acc[t], 0, 0, 0);
        }
    }

    float* sw_ = sc[w];
#pragma unroll
    for (int t = 0; t < 4; t++) {
        float b = brel[t * 16 + lm];
#pragma unroll
        for (int i = 0; i < 4; i++) {
            float v = acc[t][i] + b;
            if (RELU) v = fmaxf(v, 0.f);
            sw_[(q * 4 + i) * 68 + t * 16 + lm] = v;
        }
    }
    int rr = l >> 2, cs = l & 3;
    int node = r0 + rr;
    if (node < n) {
        const float* rp = sw_ + rr * 68 + cs * 16;
        float4 v0 = *(const float4*)(rp);
        float4 v1 = *(const float4*)(rp + 4);
        float4 v2 = *(const float4*)(rp + 8);
        float4 v3 = *(const float4*)(rp + 12);
        uint4 o0, o1;
        o0.x = (unsigned)f2b(v0.x) | ((unsigned)f2b(v0.y) << 16);
        o0.y = (unsigned)f2b(v0.z) | ((unsigned)f2b(v0.w) << 16);
        o0.z = (unsigned)f2b(v1.x) | ((unsigned)f2b(v1.y) << 16);
        o0.w = (unsigned)f2b(v1.z) | ((unsigned)f2b(v1.w) << 16);
        o1.x = (unsigned)f2b(v2.x) | ((unsigned)f2b(v2.y) << 16);
        o1.y = (unsigned)f2b(v2.z) | ((unsigned)f2b(v2.w) << 16);
        o1.z = (unsigned)f2b(v3.x) | ((unsigned)f2b(v3.y) << 16);
        o1.w = (unsigned)f2b(v3.z) | ((unsigned)f2b(v3.w) << 16);
        uint4* op = (uint4*)(hbout + (size_t)node * 64 + cs * 16);
        op[0] = o0;
        op[1] = o1;
    }
}

// ---------------- fused pool + MLP head (one block per graph) --------------
// Pool phase: 256 threads = 4 node-strides x 64 features, partials combined
// in LDS. MLP phase reads the pooled row straight from LDS.

__global__ __launch_bounds__(256) void k_poolmlp(
    const unsigned short* __restrict__ hb, const int* __restrict__ batch,
    const float* __restrict__ T, const float* __restrict__ w1,
    const float* __restrict__ b1, const float* __restrict__ w2,
    const float* __restrict__ b2, const float* __restrict__ w3,
    const float* __restrict__ b3, float* __restrict__ out, int n) {
    __shared__ float psum[4][64];
    __shared__ float pmax[4][64];
    __shared__ float sin_[193];
    __shared__ float so1[256];
    __shared__ float red[256];
    int g = blockIdx.x, t = threadIdx.x;
    int l = t & 63, c = t >> 6;

    // bounds via binary search (batch sorted)
    int lo = 0, hi = n;
    while (lo < hi) { int m = (lo + hi) >> 1; if (batch[m] < g) lo = m + 1; else hi = m; }
    int s0 = lo;
    int lo2 = s0, hi2 = n;
    while (lo2 < hi2) { int m = (lo2 + hi2) >> 1; if (batch[m] < g + 1) lo2 = m + 1; else hi2 = m; }
    int s1 = lo2;

    float sacc = 0.f, macc = -INFINITY;
    for (int nn = s0 + c; nn < s1; nn += 4) {
        float v = b2f(hb[(size_t)nn * 64 + l]);
        sacc += v;
        macc = fmaxf(macc, v);
    }
    psum[c][l] = sacc;
    pmax[c][l] = macc;
    __syncthreads();
    if (t < 64) {
        float s = (psum[0][t] + psum[1][t]) + (psum[2][t] + psum[3][t]);
        float mx = fmaxf(fmaxf(pmax[0][t], pmax[1][t]), fmaxf(pmax[2][t], pmax[3][t]));
        int cnt = s1 - s0;
        float mean = s / fmaxf((float)cnt, 1.f);
        if (cnt == 0) mx = 0.f;
        sin_[t] = mx;
        sin_[64 + t] = mean;
        sin_[128 + t] = s;
        if (t == 0) sin_[192] = T[g];
    }
    __syncthreads();

    float a = b1[t];
    for (int k = 0; k < 193; k++) a += sin_[k] * w1[k * 256 + t];
    a = fmaxf(a, 0.f);
    so1[t] = a;
    __syncthreads();
    float a2 = b2[t];
    for (int k = 0; k < 256; k++) a2 += so1[k] * w2[k * 256 + t];
    a2 = fmaxf(a2, 0.f);
    red[t] = a2 * w3[t];
    __syncthreads();
    for (int s = 128; s > 0; s >>= 1) {
        if (t < s) red[t] += red[t + s];
        __syncthreads();
    }
    if (t == 0) out[g] = red[0] + b3[0];
}

extern "C" void kernel_launch(void* const* d_in, const int* in_sizes, int n_in,
                              void* d_out, int out_size, void* d_ws, size_t ws_size,
                              hipStream_t stream) {
    const int N = N_NODES, E = N_EDGES, G = N_GRAPHS;

    const float* x = (const float*)d_in[0];
    const int* ei = (const int*)d_in[1];
    const int* batch = (const int*)d_in[2];
    const float* T = (const float*)d_in[3];
    const float* wrel[4] = {(const float*)d_in[4], (const float*)d_in[7],
                            (const float*)d_in[10], (const float*)d_in[13]};
    const float* brel[4] = {(const float*)d_in[5], (const float*)d_in[8],
                            (const float*)d_in[11], (const float*)d_in[14]};
    const float* wroot[4] = {(const float*)d_in[6], (const float*)d_in[9],
                             (const float*)d_in[12], (const float*)d_in[15]};
    const float* w1 = (const float*)d_in[16];
    const float* b1 = (const float*)d_in[17];
    const float* w2 = (const float*)d_in[18];
    const float* b2 = (const float*)d_in[19];
    const float* w3 = (const float*)d_in[20];
    const float* b3 = (const float*)d_in[21];
    float* out = (float*)d_out;

    const int* esrc = ei;
    const int* edst = ei + E;

    // workspace layout (~55 MB)
    char* ws = (char*)d_ws;
    size_t off = 0;
    auto alloc = [&](size_t bytes) {
        size_t r = off;
        off = (off + bytes + 255) & ~(size_t)255;
        return r;
    };
    int* bcnt = (int*)(ws + alloc((size_t)NB * 4));
    int2* re = (int2*)(ws + alloc((size_t)N * 8));
    unsigned int* soff = (unsigned int*)(ws + alloc((size_t)NB * CAP * 4 + 64));
    unsigned int* ebuf = (unsigned int*)(ws + alloc((size_t)NB * CAP * 4));
    unsigned short* hbA = (unsigned short*)(ws + alloc((size_t)N * 64 * 2));
    unsigned short* hbB = (unsigned short*)(ws + alloc((size_t)N * 64 * 2));
    unsigned short* aggb = (unsigned short*)(ws + alloc((size_t)N * 64 * 2));
    unsigned short* wt = (unsigned short*)(ws + alloc((size_t)4 * 64 * 128 * 2));

    // 1. prep: zero bucket counts, then mega (scatter + f2b + wprep)
    hipMemsetAsync(bcnt, 0, (size_t)NB * 4, stream);
    k_mega<<<SCAT_BLOCKS + F2B_BLOCKS + WPREP_BLOCKS, 256, 0, stream>>>(
        esrc, edst, bcnt, ebuf, (const float4*)x, (ushort4*)hbA,
        wroot[0], wrel[0], wroot[1], wrel[1],
        wroot[2], wrel[2], wroot[3], wrel[3], wt);
    k_fscatter2<<<NB, 256, 0, stream>>>(ebuf, bcnt, re, soff, N);

    // 2. four conv layers (bf16 h ping-pong, MFMA gemm)
    int agg_blocks = (N * 64 + 255) / 256;   // one wave per node
    int gemm_blocks = (N + 63) / 64;         // 64-node tile per block

    k_agg<<<agg_blocks, 256, 0, stream>>>(hbA, aggb, re, soff, N);
    k_gemm<1><<<gemm_blocks, 256, 0, stream>>>(hbA, aggb, wt + 0 * 8192, brel[0], hbB, N);

    k_agg<<<agg_blocks, 256, 0, stream>>>(hbB, aggb, re, soff, N);
    k_gemm<1><<<gemm_blocks, 256, 0, stream>>>(hbB, aggb, wt + 1 * 8192, brel[1], hbA, N);

    k_agg<<<agg_blocks, 256, 0, stream>>>(hbA, aggb, re, soff, N);
    k_gemm<1><<<gemm_blocks, 256, 0, stream>>>(hbA, aggb, wt + 2 * 8192, brel[2], hbB, N);

    k_agg<<<agg_blocks, 256, 0, stream>>>(hbB, aggb, re, soff, N);
    k_gemm<0><<<gemm_blocks, 256, 0, stream>>>(hbB, aggb, wt + 3 * 8192, brel[3], hbA, N);

    // 3. fused pooling + MLP head
    k_poolmlp<<<G, 256, 0, stream>>>(hbA, batch, T, w1, b1, w2, b2, w3, b3, out, N);
}

// Round 12
// 416.598 us; speedup vs baseline: 2.3369x; 1.0319x over previous
//
#include <hip/hip_runtime.h>
#include <hip/hip_bf16.h>
#include <math.h>

#define N_NODES 100000
#define N_EDGES 1600000
#define N_FEAT 64
#define HID 64
#define HL 256
#define N_GRAPHS 512

#define BUCKET_BITS 7
#define BUCKET_SIZE 128
#define NB ((N_NODES + BUCKET_SIZE - 1) / BUCKET_SIZE)   // 782
#define CAP 2560                   // per-bucket record capacity (mean 2046 + 11 sigma)
#define EDGES_PER_BLOCK 4096
#define SCAT_BLOCKS ((N_EDGES + EDGES_PER_BLOCK - 1) / EDGES_PER_BLOCK)  // 391
#define F2B_BLOCKS (N_NODES * 16 / 256)                                  // 6250
#define WPREP_BLOCKS 128

typedef short vbf8 __attribute__((ext_vector_type(8)));
typedef float vf4 __attribute__((ext_vector_type(4)));
typedef float vf2 __attribute__((ext_vector_type(2)));

// bf16 helpers (manual RNE; values are finite)
__device__ __forceinline__ unsigned short f2b(float f) {
    unsigned int u = __float_as_uint(f);
    return (unsigned short)((u + 0x7FFFu + ((u >> 16) & 1u)) >> 16);
}
__device__ __forceinline__ float b2f(unsigned short u) {
    return __uint_as_float(((unsigned int)u) << 16);
}
// bf16 pair -> float2 {lo, hi} (shift + and; pairs with v_pk_add_f32)
__device__ __forceinline__ vf2 bpair(unsigned int d) {
    vf2 r;
    r.x = __uint_as_float(d << 16);
    r.y = __uint_as_float(d & 0xFFFF0000u);
    return r;
}

// ---------------- mega prep: bucket-scatter + f2b + wprep in one launch ----

__global__ __launch_bounds__(256) void k_mega(
        const int* __restrict__ src, const int* __restrict__ dst,
        int* __restrict__ bcnt, unsigned int* __restrict__ ebuf,
        const float4* __restrict__ x, ushort4* __restrict__ xb,
        const float* __restrict__ wroot0, const float* __restrict__ wrel0,
        const float* __restrict__ wroot1, const float* __restrict__ wrel1,
        const float* __restrict__ wroot2, const float* __restrict__ wrel2,
        const float* __restrict__ wroot3, const float* __restrict__ wrel3,
        unsigned short* __restrict__ wt) {
    __shared__ int lh[NB];
    __shared__ int lbase[NB];
    int bid = blockIdx.x;
    int t = threadIdx.x;

    if (bid < SCAT_BLOCKS) {
        // ---- bucket scatter: packed record (src<<7)|(dst&127), fixed CAP ----
        for (int i = t; i < NB; i += 256) lh[i] = 0;
        __syncthreads();
        int i0 = bid * EDGES_PER_BLOCK;
        int i1 = min(N_EDGES, i0 + EDGES_PER_BLOCK);
        for (int i = i0 + t; i < i1; i += 256)
            atomicAdd(&lh[dst[i] >> BUCKET_BITS], 1);
        __syncthreads();
        for (int i = t; i < NB; i += 256) {
            int c = lh[i];
            lbase[i] = c ? atomicAdd(&bcnt[i], c) : 0;
            lh[i] = 0;  // reuse as local cursor
        }
        __syncthreads();
        for (int i = i0 + t; i < i1; i += 256) {
            int s = src[i], d = dst[i];
            int b = d >> BUCKET_BITS;
            int p = b * CAP + lbase[b] + atomicAdd(&lh[b], 1);
            ebuf[p] = ((unsigned int)s << 7) | (unsigned int)(d & 127);
        }
    } else if (bid < SCAT_BLOCKS + F2B_BLOCKS) {
        // ---- fp32 -> bf16 convert ----
        int i = (bid - SCAT_BLOCKS) * 256 + t;
        if (i < N_NODES * 16) {
            float4 v = x[i];
            ushort4 o;
            o.x = f2b(v.x); o.y = f2b(v.y); o.z = f2b(v.z); o.w = f2b(v.w);
            xb[i] = o;
        }
    } else {
        // ---- weight prep: Wt[layer][n][k], k = [wroot|wrel] ----
        int gi = (bid - SCAT_BLOCKS - F2B_BLOCKS) * 256 + t;
        if (gi < 4 * 64 * 128) {
            int layer = gi >> 13;
            int i = gi & 8191;
            int nn = i >> 7, k = i & 127;
            const float* wr = (layer == 0) ? wroot0 : (layer == 1) ? wroot1
                             : (layer == 2) ? wroot2 : wroot3;
            const float* wl = (layer == 0) ? wrel0 : (layer == 1) ? wrel1
                             : (layer == 2) ? wrel2 : wrel3;
            float v = (k < 64) ? wr[k * 64 + nn] : wl[(k - 64) * 64 + nn];
            wt[gi] = f2b(v);
        }
    }
}

// ---------------- per-bucket: node hist -> scan -> re{start,end} -> soff ---

__global__ __launch_bounds__(256) void k_fscatter2(const unsigned int* __restrict__ ebuf,
        const int* __restrict__ bcnt, int2* __restrict__ re,
        unsigned int* __restrict__ soff, int n) {
    __shared__ int lcnt[BUCKET_SIZE];
    __shared__ int sc[BUCKET_SIZE];
    __shared__ int cur[BUCKET_SIZE];
    int b = blockIdx.x;
    int rbase = b * CAP;
    int n0 = b * BUCKET_SIZE;
    int t = threadIdx.x;
    int cb = bcnt[b];
    if (t < BUCKET_SIZE) lcnt[t] = 0;
    __syncthreads();
    for (int r = t; r < cb; r += 256) {
        unsigned int rec = ebuf[rbase + r];
        atomicAdd(&lcnt[rec & 127u], 1);
    }
    __syncthreads();
    int v = 0;
    if (t < BUCKET_SIZE) {
        v = lcnt[t];
        sc[t] = v;
    }
    __syncthreads();
    for (int off = 1; off < BUCKET_SIZE; off <<= 1) {
        int x = 0;
        if (t < BUCKET_SIZE) {
            x = sc[t];
            if (t >= off) x += sc[t - off];
        }
        __syncthreads();
        if (t < BUCKET_SIZE) sc[t] = x;
        __syncthreads();
    }
    if (t < BUCKET_SIZE) {
        int start = rbase + sc[t] - v;   // exclusive scan
        if (n0 + t < n) re[n0 + t] = make_int2(start, start + v);
        cur[t] = start;
    }
    __syncthreads();
    for (int r = t; r < cb; r += 256) {
        unsigned int rec = ebuf[rbase + r];
        int p = atomicAdd(&cur[rec & 127u], 1);
        soff[p] = rec & ~127u;   // src * 128 byte offset
    }
    if (t < 8) soff[rbase + cb + t] = 0u;   // zero tail pad for agg over-reads
}

// ---------------- aggregation: aggb[i] = sum_{j->i} h[j] (bf16 in/out) -----

__global__ __launch_bounds__(256) void k_agg(
    const unsigned short* __restrict__ hb, unsigned short* __restrict__ aggb,
    const int2* __restrict__ re, const unsigned int* __restrict__ soff, int n) {
    int lane = threadIdx.x & 63;
    int i = (blockIdx.x * 256 + threadIdx.x) >> 6;
    if (i >= n) return;
    int q = lane >> 3;
    int sl = lane & 7;
    int2 bounds = re[i];
    int e0 = bounds.x, e1 = bounds.y;
    int iters = (e1 - e0 + 7) >> 3;
    const char* base = (const char*)hb + sl * 16;

    vf2 A[4], B[4];
#pragma unroll
    for (int f = 0; f < 4; f++) { A[f] = (vf2){0.f, 0.f}; B[f] = (vf2){0.f, 0.f}; }

    int eq = e0 + q;
    int it = 0;
    for (; it + 2 <= iters; it += 2) {
        int ea = eq + it * 8, eb = ea + 8;
        unsigned oa = __builtin_nontemporal_load(soff + ea);
        unsigned ob = __builtin_nontemporal_load(soff + eb);
        uint4 da = *(const uint4*)(base + oa);
        uint4 db = *(const uint4*)(base + ob);
        if (ea >= e1) { da.x = 0u; da.y = 0u; da.z = 0u; da.w = 0u; }
        if (eb >= e1) { db.x = 0u; db.y = 0u; db.z = 0u; db.w = 0u; }
        A[0] += bpair(da.x); A[1] += bpair(da.y);
        A[2] += bpair(da.z); A[3] += bpair(da.w);
        B[0] += bpair(db.x); B[1] += bpair(db.y);
        B[2] += bpair(db.z); B[3] += bpair(db.w);
    }
    if (it < iters) {
        int ea = eq + it * 8;
        unsigned oa = __builtin_nontemporal_load(soff + ea);
        uint4 da = *(const uint4*)(base + oa);
        if (ea >= e1) { da.x = 0u; da.y = 0u; da.z = 0u; da.w = 0u; }
        A[0] += bpair(da.x); A[1] += bpair(da.y);
        A[2] += bpair(da.z); A[3] += bpair(da.w);
    }

    float f[8];
#pragma unroll
    for (int k = 0; k < 4; k++) {
        vf2 s2 = A[k] + B[k];
        float slo = s2.x, shi = s2.y;
        slo += __shfl_xor(slo, 8);
        slo += __shfl_xor(slo, 16);
        slo += __shfl_xor(slo, 32);
        shi += __shfl_xor(shi, 8);
        shi += __shfl_xor(shi, 16);
        shi += __shfl_xor(shi, 32);
        f[2 * k] = slo;
        f[2 * k + 1] = shi;
    }
    if (q == 0) {
        uint4 o;
        o.x = (unsigned)f2b(f[0]) | ((unsigned)f2b(f[1]) << 16);
        o.y = (unsigned)f2b(f[2]) | ((unsigned)f2b(f[3]) << 16);
        o.z = (unsigned)f2b(f[4]) | ((unsigned)f2b(f[5]) << 16);
        o.w = (unsigned)f2b(f[6]) | ((unsigned)f2b(f[7]) << 16);
        *(uint4*)((char*)aggb + (size_t)i * 128 + sl * 16) = o;
    }
}

// ---------------- MFMA gemm: hbout = [relu]([hb|aggb] @ Wt^T + brel) -------

template <int RELU>
__global__ __launch_bounds__(256) void k_gemm(
    const unsigned short* __restrict__ hb, const unsigned short* __restrict__ aggb,
    const unsigned short* __restrict__ wt, const float* __restrict__ brel,
    unsigned short* __restrict__ hbout, int n) {
    __shared__ float sc[4][16 * 68];

    int tid = threadIdx.x;
    int w = tid >> 6, l = tid & 63;
    int lm = l & 15, q = l >> 4;
    int r0 = blockIdx.x * 64 + w * 16;

    int arow = r0 + lm;
    if (arow >= n) arow = n - 1;
    const unsigned short* ah = hb + (size_t)arow * 64 + q * 8;
    const unsigned short* aa = aggb + (size_t)arow * 64 + q * 8;
    vbf8 afr[4];
    afr[0] = *(const vbf8*)(ah);
    afr[1] = *(const vbf8*)(ah + 32);
    afr[2] = *(const vbf8*)(aa);
    afr[3] = *(const vbf8*)(aa + 32);

    vf4 acc[4];
#pragma unroll
    for (int t = 0; t < 4; t++) acc[t] = (vf4){0.f, 0.f, 0.f, 0.f};

#pragma unroll
    for (int t = 0; t < 4; t++) {
        const unsigned short* wrow = wt + (size_t)(t * 16 + lm) * 128 + q * 8;
#pragma unroll
        for (int s = 0; s < 4; s++) {
            vbf8 bfr = *(const vbf8*)(wrow + s * 32);
            acc[t] = __builtin_amdgcn_mfma_f32_16x16x32_bf16(afr[s], bfr, acc[t], 0, 0, 0);
        }
    }

    float* sw_ = sc[w];
#pragma unroll
    for (int t = 0; t < 4; t++) {
        float b = brel[t * 16 + lm];
#pragma unroll
        for (int i = 0; i < 4; i++) {
            float v = acc[t][i] + b;
            if (RELU) v = fmaxf(v, 0.f);
            sw_[(q * 4 + i) * 68 + t * 16 + lm] = v;
        }
    }
    int rr = l >> 2, cs = l & 3;
    int node = r0 + rr;
    if (node < n) {
        const float* rp = sw_ + rr * 68 + cs * 16;
        float4 v0 = *(const float4*)(rp);
        float4 v1 = *(const float4*)(rp + 4);
        float4 v2 = *(const float4*)(rp + 8);
        float4 v3 = *(const float4*)(rp + 12);
        uint4 o0, o1;
        o0.x = (unsigned)f2b(v0.x) | ((unsigned)f2b(v0.y) << 16);
        o0.y = (unsigned)f2b(v0.z) | ((unsigned)f2b(v0.w) << 16);
        o0.z = (unsigned)f2b(v1.x) | ((unsigned)f2b(v1.y) << 16);
        o0.w = (unsigned)f2b(v1.z) | ((unsigned)f2b(v1.w) << 16);
        o1.x = (unsigned)f2b(v2.x) | ((unsigned)f2b(v2.y) << 16);
        o1.y = (unsigned)f2b(v2.z) | ((unsigned)f2b(v2.w) << 16);
        o1.z = (unsigned)f2b(v3.x) | ((unsigned)f2b(v3.y) << 16);
        o1.w = (unsigned)f2b(v3.z) | ((unsigned)f2b(v3.w) << 16);
        uint4* op = (uint4*)(hbout + (size_t)node * 64 + cs * 16);
        op[0] = o0;
        op[1] = o1;
    }
}

// ---------------- fused pool + MLP head (one block per graph) --------------
// Matvec K-loops batched x8: 8 weight loads in flight before the FMAs, so
// the loop is load-latency/8 bound instead of fully serialized (r11: VGPR=20,
// no unroll, ~250cyc/iter).

__global__ __launch_bounds__(256) void k_poolmlp(
    const unsigned short* __restrict__ hb, const int* __restrict__ batch,
    const float* __restrict__ T, const float* __restrict__ w1,
    const float* __restrict__ b1, const float* __restrict__ w2,
    const float* __restrict__ b2, const float* __restrict__ w3,
    const float* __restrict__ b3, float* __restrict__ out, int n) {
    __shared__ float psum[4][64];
    __shared__ float pmax[4][64];
    __shared__ float sin_[200];
    __shared__ float so1[256];
    __shared__ float red[256];
    int g = blockIdx.x, t = threadIdx.x;
    int l = t & 63, c = t >> 6;

    // bounds via binary search (batch sorted)
    int lo = 0, hi = n;
    while (lo < hi) { int m = (lo + hi) >> 1; if (batch[m] < g) lo = m + 1; else hi = m; }
    int s0 = lo;
    int lo2 = s0, hi2 = n;
    while (lo2 < hi2) { int m = (lo2 + hi2) >> 1; if (batch[m] < g + 1) lo2 = m + 1; else hi2 = m; }
    int s1 = lo2;

    // pooling: unroll x4 (independent loads in flight)
    float sa0 = 0.f, sa1 = 0.f, sa2 = 0.f, sa3 = 0.f;
    float ma0 = -INFINITY, ma1 = -INFINITY, ma2 = -INFINITY, ma3 = -INFINITY;
    int nn = s0 + c;
    for (; nn + 12 < s1; nn += 16) {
        float v0 = b2f(hb[(size_t)nn * 64 + l]);
        float v1 = b2f(hb[(size_t)(nn + 4) * 64 + l]);
        float v2 = b2f(hb[(size_t)(nn + 8) * 64 + l]);
        float v3 = b2f(hb[(size_t)(nn + 12) * 64 + l]);
        sa0 += v0; sa1 += v1; sa2 += v2; sa3 += v3;
        ma0 = fmaxf(ma0, v0); ma1 = fmaxf(ma1, v1);
        ma2 = fmaxf(ma2, v2); ma3 = fmaxf(ma3, v3);
    }
    for (; nn < s1; nn += 4) {
        float v = b2f(hb[(size_t)nn * 64 + l]);
        sa0 += v;
        ma0 = fmaxf(ma0, v);
    }
    psum[c][l] = (sa0 + sa1) + (sa2 + sa3);
    pmax[c][l] = fmaxf(fmaxf(ma0, ma1), fmaxf(ma2, ma3));
    __syncthreads();
    if (t < 64) {
        float s = (psum[0][t] + psum[1][t]) + (psum[2][t] + psum[3][t]);
        float mx = fmaxf(fmaxf(pmax[0][t], pmax[1][t]), fmaxf(pmax[2][t], pmax[3][t]));
        int cnt = s1 - s0;
        float mean = s / fmaxf((float)cnt, 1.f);
        if (cnt == 0) mx = 0.f;
        sin_[t] = mx;
        sin_[64 + t] = mean;
        sin_[128 + t] = s;
        if (t == 0) {
            sin_[192] = T[g];
#pragma unroll
            for (int z = 193; z < 200; z++) sin_[z] = 0.f;  // pad for x8 batch
        }
    }
    __syncthreads();

    // layer 1: 193-K matvec, batched x8 (pad zeros make 200 safe)
    float a = b1[t];
    {
        float wv[8];
        for (int k = 0; k < 192; k += 8) {
#pragma unroll
            for (int u = 0; u < 8; u++) wv[u] = w1[(k + u) * 256 + t];
#pragma unroll
            for (int u = 0; u < 8; u++) a += sin_[k + u] * wv[u];
        }
        a += sin_[192] * w1[192 * 256 + t];
    }
    a = fmaxf(a, 0.f);
    so1[t] = a;
    __syncthreads();

    // layer 2: 256-K matvec, batched x8
    float a2 = b2[t];
    {
        float wv[8];
        for (int k = 0; k < 256; k += 8) {
#pragma unroll
            for (int u = 0; u < 8; u++) wv[u] = w2[(k + u) * 256 + t];
#pragma unroll
            for (int u = 0; u < 8; u++) a2 += so1[k + u] * wv[u];
        }
    }
    a2 = fmaxf(a2, 0.f);
    red[t] = a2 * w3[t];
    __syncthreads();
    for (int s = 128; s > 0; s >>= 1) {
        if (t < s) red[t] += red[t + s];
        __syncthreads();
    }
    if (t == 0) out[g] = red[0] + b3[0];
}

extern "C" void kernel_launch(void* const* d_in, const int* in_sizes, int n_in,
                              void* d_out, int out_size, void* d_ws, size_t ws_size,
                              hipStream_t stream) {
    const int N = N_NODES, E = N_EDGES, G = N_GRAPHS;

    const float* x = (const float*)d_in[0];
    const int* ei = (const int*)d_in[1];
    const int* batch = (const int*)d_in[2];
    const float* T = (const float*)d_in[3];
    const float* wrel[4] = {(const float*)d_in[4], (const float*)d_in[7],
                            (const float*)d_in[10], (const float*)d_in[13]};
    const float* brel[4] = {(const float*)d_in[5], (const float*)d_in[8],
                            (const float*)d_in[11], (const float*)d_in[14]};
    const float* wroot[4] = {(const float*)d_in[6], (const float*)d_in[9],
                             (const float*)d_in[12], (const float*)d_in[15]};
    const float* w1 = (const float*)d_in[16];
    const float* b1 = (const float*)d_in[17];
    const float* w2 = (const float*)d_in[18];
    const float* b2 = (const float*)d_in[19];
    const float* w3 = (const float*)d_in[20];
    const float* b3 = (const float*)d_in[21];
    float* out = (float*)d_out;

    const int* esrc = ei;
    const int* edst = ei + E;

    // workspace layout (~55 MB)
    char* ws = (char*)d_ws;
    size_t off = 0;
    auto alloc = [&](size_t bytes) {
        size_t r = off;
        off = (off + bytes + 255) & ~(size_t)255;
        return r;
    };
    int* bcnt = (int*)(ws + alloc((size_t)NB * 4));
    int2* re = (int2*)(ws + alloc((size_t)N * 8));
    unsigned int* soff = (unsigned int*)(ws + alloc((size_t)NB * CAP * 4 + 64));
    unsigned int* ebuf = (unsigned int*)(ws + alloc((size_t)NB * CAP * 4));
    unsigned short* hbA = (unsigned short*)(ws + alloc((size_t)N * 64 * 2));
    unsigned short* hbB = (unsigned short*)(ws + alloc((size_t)N * 64 * 2));
    unsigned short* aggb = (unsigned short*)(ws + alloc((size_t)N * 64 * 2));
    unsigned short* wt = (unsigned short*)(ws + alloc((size_t)4 * 64 * 128 * 2));

    // 1. prep: zero bucket counts, then mega (scatter + f2b + wprep)
    hipMemsetAsync(bcnt, 0, (size_t)NB * 4, stream);
    k_mega<<<SCAT_BLOCKS + F2B_BLOCKS + WPREP_BLOCKS, 256, 0, stream>>>(
        esrc, edst, bcnt, ebuf, (const float4*)x, (ushort4*)hbA,
        wroot[0], wrel[0], wroot[1], wrel[1],
        wroot[2], wrel[2], wroot[3], wrel[3], wt);
    k_fscatter2<<<NB, 256, 0, stream>>>(ebuf, bcnt, re, soff, N);

    // 2. four conv layers (bf16 h ping-pong, MFMA gemm)
    int agg_blocks = (N * 64 + 255) / 256;   // one wave per node
    int gemm_blocks = (N + 63) / 64;         // 64-node tile per block

    k_agg<<<agg_blocks, 256, 0, stream>>>(hbA, aggb, re, soff, N);
    k_gemm<1><<<gemm_blocks, 256, 0, stream>>>(hbA, aggb, wt + 0 * 8192, brel[0], hbB, N);

    k_agg<<<agg_blocks, 256, 0, stream>>>(hbB, aggb, re, soff, N);
    k_gemm<1><<<gemm_blocks, 256, 0, stream>>>(hbB, aggb, wt + 1 * 8192, brel[1], hbA, N);

    k_agg<<<agg_blocks, 256, 0, stream>>>(hbA, aggb, re, soff, N);
    k_gemm<1><<<gemm_blocks, 256, 0, stream>>>(hbA, aggb, wt + 2 * 8192, brel[2], hbB, N);

    k_agg<<<agg_blocks, 256, 0, stream>>>(hbB, aggb, re, soff, N);
    k_gemm<0><<<gemm_blocks, 256, 0, stream>>>(hbB, aggb, wt + 3 * 8192, brel[3], hbA, N);

    // 3. fused pooling + MLP head
    k_poolmlp<<<G, 256, 0, stream>>>(hbA, batch, T, w1, b1, w2, b2, w3, b3, out, N);
}